// Round 12
// baseline (1617.039 us; speedup 1.0000x reference)
//
#include <hip/hip_runtime.h>
#include <math.h>

#define TSAMP 32768
#define CCH 128
#define NBATCH 8
#define NEV 32
#define NROWS 256   // NBATCH*NEV
#define NATOMS 512
#define ASIZE 512
#define NTRANS 64
#define TSIZE 8192

#define DRY_SCALE 16777216.0f               // 2^24
#define IMP_SCALE 64.0f                     // 2^6
#define WET_DESCALE 9.313225746154785e-10f  // 2^-30

// LDS skew for stride-4 lane patterns: 8-way conflict -> 2-way (free)
#define EPAD(i) ((i) + ((i) >> 5))

typedef _Float16 f16x8 __attribute__((ext_vector_type(8)));
typedef _Float16 f16x4 __attribute__((ext_vector_type(4)));
typedef float f32x4 __attribute__((ext_vector_type(4)));

// monotone float <-> uint transform for atomicMax-based float max
__device__ __forceinline__ unsigned f2u(float f) {
  unsigned u = __float_as_uint(f);
  return (u & 0x80000000u) ? ~u : (u | 0x80000000u);
}
__device__ __forceinline__ float u2f(unsigned u) {
  return (u & 0x80000000u) ? __uint_as_float(u & 0x7FFFFFFFu)
                           : __uint_as_float(~u);
}

// activations stored [B][T][C] (c contiguous).

// ------------------------------------------------------------------
// K-prep: split conv weights + filter bank to f16 hi/lo; zero sums + cmax.
__global__ __launch_bounds__(256) void k_prep(const float* __restrict__ wn,
                                              const float* __restrict__ bank,
                                              _Float16* __restrict__ whi,
                                              _Float16* __restrict__ wlo,
                                              _Float16* __restrict__ bhi,
                                              _Float16* __restrict__ blo,
                                              double* __restrict__ sums,
                                              unsigned* __restrict__ cmax) {
  const int i = blockIdx.x * 256 + threadIdx.x;
  if (i < 16) sums[i] = 0.0;
  if (i < 1024) cmax[i] = 0u;               // == -inf under f2u ordering
  if (i < 245760) {
    const int ci = i & 127;
    int r = i >> 7;
    const int o = r & 127;
    r >>= 7;
    const int k = r % 3;
    const int l = r / 3;
    const float w = wn[(((size_t)l*128 + o)*128 + ci)*3 + k];
    const _Float16 hi = (_Float16)w;
    whi[i] = hi;
    wlo[i] = (_Float16)(w - (float)hi);
  } else if (i < 311296) {
    const int j = i - 245760;
    const float w = bank[j];
    const _Float16 hi = (_Float16)w;
    bhi[j] = hi;
    blo[j] = (_Float16)(w - (float)hi);
  }
}

// K0: zero wet accumulator + drev zero-pad tail
__global__ __launch_bounds__(256) void k_zero(float* __restrict__ wet,
                                              _Float16* __restrict__ drev) {
  int i = blockIdx.x * 256 + threadIdx.x;
  if (i < NBATCH * TSAMP) wet[i] = 0.f;
  if (i < 1088) drev[TSAMP + i] = (_Float16)0.f;
}

// ------------------------------------------------------------------
// K1: front filter bank, 128-t blocks; wave tile 64c x 64t (os=4, ts=4):
// halves ds_read_b128 count per MFMA vs 32x128 tiling.
__global__ __launch_bounds__(256) void k_front_mfma(
    const float* __restrict__ x, const _Float16* __restrict__ bhi,
    const _Float16* __restrict__ blo, float* __restrict__ h) {
  __shared__ _Float16 shi[8*664];
  __shared__ _Float16 slo[8*664];
  const int t0 = blockIdx.x * 128;
  const int b  = blockIdx.y;
  const float* xb = x + (size_t)b*TSAMP;
  const int tid = threadIdx.x;

  for (int flat = tid; flat < 8*632; flat += 256) {
    const int p = flat / 632;
    const int q = flat - p*632;
    const int g = t0 - 256 + q + p;
    const float v = (g >= 0 && g < TSAMP) ? xb[g] : 0.f;
    const _Float16 hi = (_Float16)v;
    shi[p*664 + q] = hi;
    slo[p*664 + q] = (_Float16)(v - (float)hi);
  }
  __syncthreads();

  const int wv = tid >> 6;
  const int lane = tid & 63;
  const int n = lane & 15;
  const int quad = lane >> 4;
  const int c0  = (wv & 1) * 64;
  const int t0w = (wv >> 1) * 64;
  const int ph = n & 7;
  const int nb = n & 8;

  f32x4 acc[4][4];
#pragma unroll
  for (int i = 0; i < 4; ++i)
#pragma unroll
    for (int j = 0; j < 4; ++j) acc[i][j] = (f32x4){0.f,0.f,0.f,0.f};

  for (int kc = 0; kc < 16; ++kc) {
    const int kb = kc*32 + quad*8;
    f16x8 xh[4], xl[4];
#pragma unroll
    for (int u = 0; u < 4; ++u) {
      const int a = ph*664 + t0w + u*16 + nb + kb;
      xh[u] = *(const f16x8*)(shi + a);
      xl[u] = *(const f16x8*)(slo + a);
    }
#pragma unroll
    for (int os = 0; os < 4; ++os) {
      const size_t ao = (size_t)(c0 + os*16 + n)*512 + kb;
      const f16x8 ahi = *(const f16x8*)(bhi + ao);
      const f16x8 alo = *(const f16x8*)(blo + ao);
#pragma unroll
      for (int u = 0; u < 4; ++u) {
        f32x4 a4 = acc[os][u];
        a4 = __builtin_amdgcn_mfma_f32_16x16x32_f16(ahi, xh[u], a4, 0, 0, 0);
        a4 = __builtin_amdgcn_mfma_f32_16x16x32_f16(alo, xh[u], a4, 0, 0, 0);
        a4 = __builtin_amdgcn_mfma_f32_16x16x32_f16(ahi, xl[u], a4, 0, 0, 0);
        acc[os][u] = a4;
      }
    }
  }

  float* hb = h + (size_t)b*TSAMP*CCH;
#pragma unroll
  for (int os = 0; os < 4; ++os) {
    const int cb = c0 + os*16 + quad*4;
#pragma unroll
    for (int ts = 0; ts < 4; ++ts) {
      const int t = t0 + t0w + ts*16 + n;
      *(f32x4*)(hb + (size_t)t*CCH + cb) = acc[os][ts];
    }
  }
}

// ------------------------------------------------------------------
// K2a: d=27 dilated conv, 128o x 80t block; wave 64o x (48|32)t.
__global__ __launch_bounds__(256) void k_dil80(
    const float* __restrict__ hin0, const _Float16* __restrict__ whi,
    const _Float16* __restrict__ wlo, const float* __restrict__ bias,
    float* __restrict__ hout0) {
  const int d = 27;
  extern __shared__ _Float16 sh[];
  const int twin = 80 + 2*d;              // 134
  _Float16* shi = sh;
  _Float16* slo = sh + twin*136;
  const int t0 = blockIdx.x * 80;
  const size_t bs = (size_t)blockIdx.y * CCH * TSAMP;
  const float* __restrict__ hin = hin0 + bs;
  float* __restrict__ hout = hout0 + bs;
  const int tid = threadIdx.x;

  for (int flat = tid; flat < twin*32; flat += 256) {
    const int tw = flat >> 5;
    const int c4 = (flat & 31) << 2;
    const int g = t0 - d + tw;
    float4 v = {0.f, 0.f, 0.f, 0.f};
    if (g >= 0 && g < TSAMP) v = *(const float4*)(hin + (size_t)g*CCH + c4);
    f16x4 hv, lv;
    hv[0] = (_Float16)v.x; hv[1] = (_Float16)v.y;
    hv[2] = (_Float16)v.z; hv[3] = (_Float16)v.w;
    lv[0] = (_Float16)(v.x - (float)hv[0]); lv[1] = (_Float16)(v.y - (float)hv[1]);
    lv[2] = (_Float16)(v.z - (float)hv[2]); lv[3] = (_Float16)(v.w - (float)hv[3]);
    *(f16x4*)(shi + tw*136 + c4) = hv;
    *(f16x4*)(slo + tw*136 + c4) = lv;
  }
  __syncthreads();

  const int wv = tid >> 6;
  const int lane = tid & 63;
  const int n = lane & 15;
  const int quad = lane >> 4;
  const int o0 = (wv & 1) * 64;
  const int tg = wv >> 1;
  const int tsBeg = tg ? 3 : 0;
  const int tsN   = tg ? 2 : 3;

  f32x4 acc[4][3];
#pragma unroll
  for (int i = 0; i < 4; ++i)
#pragma unroll
    for (int j = 0; j < 3; ++j) acc[i][j] = (f32x4){0.f,0.f,0.f,0.f};

  for (int k = 0; k < 3; ++k) {
    for (int kc = 0; kc < 4; ++kc) {
      const int cib = kc*32 + quad*8;
      f16x8 bh[3], bl[3];
#pragma unroll
      for (int u = 0; u < 3; ++u) {
        if (u < tsN) {
          const int a = ((tsBeg + u)*16 + n + k*d)*136 + cib;
          bh[u] = *(const f16x8*)(shi + a);
          bl[u] = *(const f16x8*)(slo + a);
        }
      }
#pragma unroll
      for (int os = 0; os < 4; ++os) {
        const size_t wo = ((size_t)k*128 + (o0 + os*16 + n))*128 + cib;
        const f16x8 ahi = *(const f16x8*)(whi + wo);
        const f16x8 alo = *(const f16x8*)(wlo + wo);
#pragma unroll
        for (int u = 0; u < 3; ++u) {
          if (u < tsN) {
            f32x4 a4 = acc[os][u];
            a4 = __builtin_amdgcn_mfma_f32_16x16x32_f16(ahi, bh[u], a4, 0, 0, 0);
            a4 = __builtin_amdgcn_mfma_f32_16x16x32_f16(alo, bh[u], a4, 0, 0, 0);
            a4 = __builtin_amdgcn_mfma_f32_16x16x32_f16(ahi, bl[u], a4, 0, 0, 0);
            acc[os][u] = a4;
          }
        }
      }
    }
  }

#pragma unroll
  for (int os = 0; os < 4; ++os) {
    const int ob = o0 + os*16 + quad*4;
    const f32x4 bs4 = *(const f32x4*)(bias + ob);
#pragma unroll
    for (int u = 0; u < 3; ++u) {
      if (u < tsN) {
        const int ts = tsBeg + u;
        const int t = t0 + ts*16 + n;
        if (t < TSAMP) {
          const int tw = ts*16 + n + d;
          const f16x4 phv = *(const f16x4*)(shi + tw*136 + ob);
          const f16x4 plv = *(const f16x4*)(slo + tw*136 + ob);
          f32x4 res;
#pragma unroll
          for (int r = 0; r < 4; ++r) {
            float v = acc[os][u][r] + bs4[r];
            v = v > 0.f ? v : 0.2f*v;
            res[r] = (float)phv[r] + (float)plv[r] + v;
          }
          *(f32x4*)(hout + (size_t)t*CCH + ob) = res;
        }
      }
    }
  }
}

// ------------------------------------------------------------------
// K2b: 128-t dilated conv (d<=9); wave tile 64o x 64t.
__global__ __launch_bounds__(256) void k_dil128(
    const float* __restrict__ hin0, const _Float16* __restrict__ whi,
    const _Float16* __restrict__ wlo, const float* __restrict__ bias,
    float* __restrict__ hout0, const int d) {
  extern __shared__ _Float16 sh[];
  const int twin = 128 + 2*d;
  _Float16* shi = sh;
  _Float16* slo = sh + twin*136;
  const int t0 = blockIdx.x * 128;
  const size_t bs = (size_t)blockIdx.y * CCH * TSAMP;
  const float* __restrict__ hin = hin0 + bs;
  float* __restrict__ hout = hout0 + bs;
  const int tid = threadIdx.x;

  for (int flat = tid; flat < twin*32; flat += 256) {
    const int tw = flat >> 5;
    const int c4 = (flat & 31) << 2;
    const int g = t0 - d + tw;
    float4 v = {0.f, 0.f, 0.f, 0.f};
    if (g >= 0 && g < TSAMP) v = *(const float4*)(hin + (size_t)g*CCH + c4);
    f16x4 hv, lv;
    hv[0] = (_Float16)v.x; hv[1] = (_Float16)v.y;
    hv[2] = (_Float16)v.z; hv[3] = (_Float16)v.w;
    lv[0] = (_Float16)(v.x - (float)hv[0]); lv[1] = (_Float16)(v.y - (float)hv[1]);
    lv[2] = (_Float16)(v.z - (float)hv[2]); lv[3] = (_Float16)(v.w - (float)hv[3]);
    *(f16x4*)(shi + tw*136 + c4) = hv;
    *(f16x4*)(slo + tw*136 + c4) = lv;
  }
  __syncthreads();

  const int wv = tid >> 6;
  const int lane = tid & 63;
  const int n = lane & 15;
  const int quad = lane >> 4;
  const int o0  = (wv & 1) * 64;
  const int t0w = (wv >> 1) * 64;

  f32x4 acc[4][4];
#pragma unroll
  for (int i = 0; i < 4; ++i)
#pragma unroll
    for (int j = 0; j < 4; ++j) acc[i][j] = (f32x4){0.f,0.f,0.f,0.f};

  for (int k = 0; k < 3; ++k) {
    for (int kc = 0; kc < 4; ++kc) {
      const int cib = kc*32 + quad*8;
      f16x8 bh[4], bl[4];
#pragma unroll
      for (int u = 0; u < 4; ++u) {
        const int a = (t0w + u*16 + n + k*d)*136 + cib;
        bh[u] = *(const f16x8*)(shi + a);
        bl[u] = *(const f16x8*)(slo + a);
      }
#pragma unroll
      for (int os = 0; os < 4; ++os) {
        const size_t wo = ((size_t)k*128 + (o0 + os*16 + n))*128 + cib;
        const f16x8 ahi = *(const f16x8*)(whi + wo);
        const f16x8 alo = *(const f16x8*)(wlo + wo);
#pragma unroll
        for (int u = 0; u < 4; ++u) {
          f32x4 a4 = acc[os][u];
          a4 = __builtin_amdgcn_mfma_f32_16x16x32_f16(ahi, bh[u], a4, 0, 0, 0);
          a4 = __builtin_amdgcn_mfma_f32_16x16x32_f16(alo, bh[u], a4, 0, 0, 0);
          a4 = __builtin_amdgcn_mfma_f32_16x16x32_f16(ahi, bl[u], a4, 0, 0, 0);
          acc[os][u] = a4;
        }
      }
    }
  }

#pragma unroll
  for (int os = 0; os < 4; ++os) {
    const int ob = o0 + os*16 + quad*4;
    const f32x4 bs4 = *(const f32x4*)(bias + ob);
#pragma unroll
    for (int ts = 0; ts < 4; ++ts) {
      const int t = t0 + t0w + ts*16 + n;
      const int tw = t0w + ts*16 + n + d;
      const f16x4 phv = *(const f16x4*)(shi + tw*136 + ob);
      const f16x4 plv = *(const f16x4*)(slo + tw*136 + ob);
      f32x4 res;
#pragma unroll
      for (int r = 0; r < 4; ++r) {
        float v = acc[os][ts][r] + bs4[r];
        v = v > 0.f ? v : 0.2f*v;
        res[r] = (float)phv[r] + (float)plv[r] + v;
      }
      *(f32x4*)(hout + (size_t)t*CCH + ob) = res;
    }
  }
}

// ------------------------------------------------------------------
// K2c: LAST layer (d=1), wave 64o x 64t, fused stats/attn/ctx epilogue.
__global__ __launch_bounds__(256) void k_dil_last(
    const float* __restrict__ hin0, const _Float16* __restrict__ whi,
    const _Float16* __restrict__ wlo, const float* __restrict__ bias,
    float* __restrict__ hout0, const int d,
    const float* __restrict__ aw, double* __restrict__ sums,
    float* __restrict__ attnraw, unsigned* __restrict__ cmax, const int bb0) {
  extern __shared__ _Float16 sh[];
  const int twin = 128 + 2*d;
  _Float16* shi = sh;
  _Float16* slo = sh + twin*136;
  __shared__ float attl[4*64];
  __shared__ double sred[8];
  const int t0 = blockIdx.x * 128;
  const int b = bb0 + blockIdx.y;
  const size_t bs = (size_t)blockIdx.y * CCH * TSAMP;
  const float* __restrict__ hin = hin0 + bs;
  float* __restrict__ hout = hout0 + bs;
  const int tid = threadIdx.x;

  for (int flat = tid; flat < twin*32; flat += 256) {
    const int tw = flat >> 5;
    const int c4 = (flat & 31) << 2;
    const int g = t0 - d + tw;
    float4 v = {0.f, 0.f, 0.f, 0.f};
    if (g >= 0 && g < TSAMP) v = *(const float4*)(hin + (size_t)g*CCH + c4);
    f16x4 hv, lv;
    hv[0] = (_Float16)v.x; hv[1] = (_Float16)v.y;
    hv[2] = (_Float16)v.z; hv[3] = (_Float16)v.w;
    lv[0] = (_Float16)(v.x - (float)hv[0]); lv[1] = (_Float16)(v.y - (float)hv[1]);
    lv[2] = (_Float16)(v.z - (float)hv[2]); lv[3] = (_Float16)(v.w - (float)hv[3]);
    *(f16x4*)(shi + tw*136 + c4) = hv;
    *(f16x4*)(slo + tw*136 + c4) = lv;
  }
  __syncthreads();

  const int wv = tid >> 6;
  const int lane = tid & 63;
  const int n = lane & 15;
  const int quad = lane >> 4;
  const int o0  = (wv & 1) * 64;
  const int t0w = (wv >> 1) * 64;

  f32x4 acc[4][4];
#pragma unroll
  for (int i = 0; i < 4; ++i)
#pragma unroll
    for (int j = 0; j < 4; ++j) acc[i][j] = (f32x4){0.f,0.f,0.f,0.f};

  for (int k = 0; k < 3; ++k) {
    for (int kc = 0; kc < 4; ++kc) {
      const int cib = kc*32 + quad*8;
      f16x8 bh[4], bl[4];
#pragma unroll
      for (int u = 0; u < 4; ++u) {
        const int a = (t0w + u*16 + n + k*d)*136 + cib;
        bh[u] = *(const f16x8*)(shi + a);
        bl[u] = *(const f16x8*)(slo + a);
      }
#pragma unroll
      for (int os = 0; os < 4; ++os) {
        const size_t wo = ((size_t)k*128 + (o0 + os*16 + n))*128 + cib;
        const f16x8 ahi = *(const f16x8*)(whi + wo);
        const f16x8 alo = *(const f16x8*)(wlo + wo);
#pragma unroll
        for (int u = 0; u < 4; ++u) {
          f32x4 a4 = acc[os][u];
          a4 = __builtin_amdgcn_mfma_f32_16x16x32_f16(ahi, bh[u], a4, 0, 0, 0);
          a4 = __builtin_amdgcn_mfma_f32_16x16x32_f16(alo, bh[u], a4, 0, 0, 0);
          a4 = __builtin_amdgcn_mfma_f32_16x16x32_f16(ahi, bl[u], a4, 0, 0, 0);
          acc[os][u] = a4;
        }
      }
    }
  }

  double s = 0.0, s2 = 0.0;
  float pa[4] = {0.f, 0.f, 0.f, 0.f};
  f32x4 cm[4];
#pragma unroll
  for (int i = 0; i < 4; ++i)
    cm[i] = (f32x4){-3.4e38f, -3.4e38f, -3.4e38f, -3.4e38f};

#pragma unroll
  for (int os = 0; os < 4; ++os) {
    const int ob = o0 + os*16 + quad*4;
    const f32x4 bs4 = *(const f32x4*)(bias + ob);
    const f32x4 awv = *(const f32x4*)(aw + ob);
#pragma unroll
    for (int ts = 0; ts < 4; ++ts) {
      const int t = t0 + t0w + ts*16 + n;
      const int tw = t0w + ts*16 + n + d;
      const f16x4 phv = *(const f16x4*)(shi + tw*136 + ob);
      const f16x4 plv = *(const f16x4*)(slo + tw*136 + ob);
      f32x4 res;
      float dotp = 0.f;
#pragma unroll
      for (int r = 0; r < 4; ++r) {
        float v = acc[os][ts][r] + bs4[r];
        v = v > 0.f ? v : 0.2f*v;
        const float hv = (float)phv[r] + (float)plv[r] + v;
        res[r] = hv;
        s += (double)hv; s2 += (double)hv*(double)hv;
        dotp += hv * awv[r];
        cm[os][r] = fmaxf(cm[os][r], hv);
      }
      pa[ts] += dotp;
      *(f32x4*)(hout + (size_t)t*CCH + ob) = res;
    }
  }

  // attn logits: reduce over o within wave (quad bits), stash per t-half
#pragma unroll
  for (int ts = 0; ts < 4; ++ts) {
    pa[ts] += __shfl_xor(pa[ts], 16);
    pa[ts] += __shfl_xor(pa[ts], 32);
  }
  if (quad == 0) {
#pragma unroll
    for (int ts = 0; ts < 4; ++ts) attl[wv*64 + ts*16 + n] = pa[ts];
  }
  // per-c max: reduce over n bits, then device atomicMax (orderable uint)
#pragma unroll
  for (int mk = 1; mk <= 8; mk <<= 1)
#pragma unroll
    for (int os = 0; os < 4; ++os)
#pragma unroll
      for (int r = 0; r < 4; ++r)
        cm[os][r] = fmaxf(cm[os][r], __shfl_xor(cm[os][r], mk));
  if (n == 0) {
#pragma unroll
    for (int os = 0; os < 4; ++os) {
      const int ob = o0 + os*16 + quad*4;
#pragma unroll
      for (int r = 0; r < 4; ++r)
        atomicMax(&cmax[b*128 + ob + r], f2u(cm[os][r]));
    }
  }
  for (int sft = 32; sft; sft >>= 1) { s += __shfl_down(s, sft); s2 += __shfl_down(s2, sft); }
  if (lane == 0) { sred[wv*2] = s; sred[wv*2+1] = s2; }
  __syncthreads();
  // wave w covers t-half (w>>1), o-half (w&1): combine o-halves per t-half
  if (tid < 128)
    attnraw[(size_t)b*TSAMP + t0 + tid] =
        attl[(tid >> 6)*128 + (tid & 63)] + attl[(tid >> 6)*128 + 64 + (tid & 63)];
  if (tid == 0) {
    atomicAdd(&sums[b*2],   sred[0] + sred[2] + sred[4] + sred[6]);
    atomicAdd(&sums[b*2+1], sred[1] + sred[3] + sred[5] + sred[7]);
  }
}

// ------------------------------------------------------------------
// K-finish: per-batch scale + context (from cmax atomics) + room + mix.
__global__ __launch_bounds__(128) void k_finish(
    const double* __restrict__ sums, const unsigned* __restrict__ cmax,
    const float* __restrict__ room_w, const float* __restrict__ room_b,
    const float* __restrict__ mix_w, const float* __restrict__ mix_b,
    float* __restrict__ scal, float* __restrict__ roomp, float* __restrict__ mix) {
  const int b = blockIdx.x;
  const int tid = threadIdx.x;
  __shared__ float bs;
  __shared__ float ctx[128];
  if (tid == 0) {
    const double nn = (double)CCH * (double)TSAMP;
    const double mean = sums[b*2] / nn;
    double var = sums[b*2+1] / nn - mean*mean;
    if (var < 0.0) var = 0.0;
    const float sc = (float)(1.0 / (sqrt(var) + 1e-8));
    bs = sc;
    scal[b] = sc;
  }
  __syncthreads();
  ctx[tid] = u2f(cmax[b*128 + tid]) * bs;
  __syncthreads();
  if (tid < 8) {
    const int r = tid;
    float acc = room_b[r];
    for (int c = 0; c < CCH; ++c) acc += ctx[c] * room_w[c*8 + r];
    float mm = acc;
    for (int s = 1; s < 8; s <<= 1) mm = fmaxf(mm, __shfl_xor(mm, s, 8));
    const float e = expf(acc - mm);
    float ss = e;
    for (int s = 1; s < 8; s <<= 1) ss += __shfl_xor(ss, s, 8);
    roomp[b*8 + r] = e / ss;
  } else if (tid == 8) {
    float a = mix_b[0];
    for (int c = 0; c < CCH; ++c) a += ctx[c] * mix_w[c];
    mix[b] = 1.f/(1.f+expf(-a));
  }
}

// ------------------------------------------------------------------
// K7a: per-2048-chunk top-32 (sigmoid fused into staging).
__global__ __launch_bounds__(256) void k_topk1(const float* __restrict__ raw,
                                               const float* __restrict__ scal,
                                               const float* __restrict__ ab,
                                               float* __restrict__ cv,
                                               int* __restrict__ cidx) {
  const int ch = blockIdx.x, b = blockIdx.y;
  const float sc = scal[b], bb_ = ab[0];
  const float* a = raw + (size_t)b*TSAMP + ch*2048;
  __shared__ float v[2048];
  __shared__ float rv[4]; __shared__ int ri[4];
  const int tid = threadIdx.x;
  for (int i = tid; i < 2048; i += 256)
    v[i] = 1.f/(1.f+expf(-(a[i]*sc + bb_)));
  __syncthreads();
  for (int e = 0; e < NEV; ++e) {
    float bv = -1e30f; int bi = 0;
    for (int i = tid; i < 2048; i += 256) {
      const float x = v[i];
      if (x > bv) { bv = x; bi = i; }
    }
    for (int s = 32; s; s >>= 1) {
      const float ov = __shfl_down(bv, s); const int oi = __shfl_down(bi, s);
      if (ov > bv || (ov == bv && oi < bi)) { bv = ov; bi = oi; }
    }
    if ((tid & 63) == 0) { rv[tid >> 6] = bv; ri[tid >> 6] = bi; }
    __syncthreads();
    if (tid == 0) {
      int bb = 0;
      for (int w2 = 1; w2 < 4; ++w2)
        if (rv[w2] > rv[bb] || (rv[w2] == rv[bb] && ri[w2] < ri[bb])) bb = w2;
      cv[(b*16 + ch)*NEV + e] = rv[bb];
      cidx[(b*16 + ch)*NEV + e] = ch*2048 + ri[bb];
      v[ri[bb]] = -1e30f;
    }
    __syncthreads();
  }
}

// K7b: final top-32 over 512 candidates
__global__ __launch_bounds__(512) void k_topk2(const float* __restrict__ cv,
                                               const int* __restrict__ ci_,
                                               float* __restrict__ vals,
                                               int* __restrict__ idxs) {
  const int b = blockIdx.x;
  const int tid = threadIdx.x;
  float my = cv[b*512 + tid];
  int   mi = ci_[b*512 + tid];
  __shared__ float rv[8]; __shared__ int ri[8];
  __shared__ float bvs; __shared__ int bis;
  for (int e = 0; e < NEV; ++e) {
    float bv = my; int bi = mi;
    for (int s = 32; s; s >>= 1) {
      const float ov = __shfl_down(bv, s); const int oi = __shfl_down(bi, s);
      if (ov > bv || (ov == bv && oi < bi)) { bv = ov; bi = oi; }
    }
    if ((tid & 63) == 0) { rv[tid >> 6] = bv; ri[tid >> 6] = bi; }
    __syncthreads();
    if (tid == 0) {
      int bb = 0;
      for (int w2 = 1; w2 < 8; ++w2)
        if (rv[w2] > rv[bb] || (rv[w2] == rv[bb] && ri[w2] < ri[bb])) bb = w2;
      vals[b*NEV + e] = rv[bb]; idxs[b*NEV + e] = ri[bb];
      bvs = rv[bb]; bis = ri[bb];
    }
    __syncthreads();
    if (mi == bis && my == bvs) my = -1e30f;
    __syncthreads();
  }
}

// ------------------------------------------------------------------
__device__ __forceinline__ float blk_max128(float v, float* red) {
  const int tid = threadIdx.x;
  red[tid] = v; __syncthreads();
  for (int s = 64; s > 0; s >>= 1) {
    if (tid < s) red[tid] = fmaxf(red[tid], red[tid + s]);
    __syncthreads();
  }
  const float r = red[0]; __syncthreads();
  return r;
}
__device__ __forceinline__ float blk_sum128(float v, float* red) {
  const int tid = threadIdx.x;
  red[tid] = v; __syncthreads();
  for (int s = 64; s > 0; s >>= 1) {
    if (tid < s) red[tid] += red[tid + s];
    __syncthreads();
  }
  const float r = red[0]; __syncthreads();
  return r;
}
__device__ __forceinline__ float mlp_hidden3(float latv, const float* __restrict__ hw,
                                             const float* __restrict__ hb, float* xa) {
  const int tid = threadIdx.x;
  float cur = latv;
  for (int i = 0; i < 3; ++i) {
    xa[tid] = cur; __syncthreads();
    const float* W = hw + (size_t)i*CCH*CCH;
    float acc = hb[i*CCH + tid];
    for (int c = 0; c < CCH; ++c) acc += xa[c] * W[c*CCH + tid];
    cur = acc > 0.f ? acc : 0.2f*acc;
    __syncthreads();
  }
  return cur;
}

// K8: lat + all three MLPs + softmaxes + amps. One 128-thread block per event.
__global__ __launch_bounds__(128) void k_mlp(
    const float* __restrict__ h, const float* __restrict__ scal,
    const float* __restrict__ vals, const int* __restrict__ idxs,
    const float* __restrict__ a_hw, const float* __restrict__ a_hb,
    const float* __restrict__ a_ow, const float* __restrict__ a_ob,
    const float* __restrict__ t_hw, const float* __restrict__ t_hb,
    const float* __restrict__ t_ow, const float* __restrict__ t_ob,
    const float* __restrict__ m_hw, const float* __restrict__ m_hb,
    const float* __restrict__ m_ow, const float* __restrict__ m_ob,
    float* __restrict__ p_atoms, float* __restrict__ p_trans, float* __restrict__ amps) {
  const int row = blockIdx.x;
  const int b = row >> 5;
  const int tid = threadIdx.x;
  __shared__ float xa[CCH];
  __shared__ float red[CCH];
  const int t = idxs[row];
  const float latv = h[((size_t)b*TSAMP + t)*CCH + tid] * scal[b] * vals[row];

  {
    const float cur = mlp_hidden3(latv, a_hw, a_hb, xa);
    xa[tid] = cur; __syncthreads();
    float l0 = a_ob[tid], l1 = a_ob[tid+128], l2 = a_ob[tid+256], l3 = a_ob[tid+384];
    for (int c = 0; c < CCH; ++c) {
      const float xv = xa[c];
      const float* W = a_ow + (size_t)c*NATOMS + tid;
      l0 += xv*W[0]; l1 += xv*W[128]; l2 += xv*W[256]; l3 += xv*W[384];
    }
    const float mx = blk_max128(fmaxf(fmaxf(l0,l1), fmaxf(l2,l3)), red);
    const float e0 = expf(l0-mx), e1 = expf(l1-mx), e2 = expf(l2-mx), e3 = expf(l3-mx);
    const float inv = 1.f / blk_sum128(e0+e1+e2+e3, red);
    float* pa = p_atoms + (size_t)row*NATOMS;
    pa[tid] = e0*inv; pa[tid+128] = e1*inv; pa[tid+256] = e2*inv; pa[tid+384] = e3*inv;
  }
  {
    const float cur = mlp_hidden3(latv, t_hw, t_hb, xa);
    xa[tid] = cur; __syncthreads();
    float lg = -3.4e38f;
    if (tid < NTRANS) {
      float acc = t_ob[tid];
      for (int c = 0; c < CCH; ++c) acc += xa[c]*t_ow[c*NTRANS + tid];
      lg = acc;
    }
    const float mt = blk_max128(lg, red);
    const float et = (tid < NTRANS) ? expf(lg - mt) : 0.f;
    const float st = blk_sum128(et, red);
    if (tid < NTRANS) p_trans[(size_t)row*NTRANS + tid] = et/st;
  }
  {
    const float cur = mlp_hidden3(latv, m_hw, m_hb, xa);
    const float s = blk_sum128(cur * m_ow[tid], red);
    if (tid == 0) { const float v = s + m_ob[0]; amps[row] = v*v; }
  }
}

// K9: atoms_vec[row,:] = p_atoms[row] @ atoms_dict (512x512)
__global__ __launch_bounds__(256) void k_atoms_mm(const float* __restrict__ p_atoms,
                                                  const float* __restrict__ dict,
                                                  float* __restrict__ av) {
  const int row = blockIdx.x;
  __shared__ float p[NATOMS];
  for (int i = threadIdx.x; i < NATOMS; i += 256) p[i] = p_atoms[(size_t)row*NATOMS + i];
  __syncthreads();
  const int s0 = threadIdx.x*2;
  float a0=0, a1=0;
  for (int a = 0; a < NATOMS; ++a) {
    const float pa = p[a];
    const float2 dv = *(const float2*)(dict + (size_t)a*ASIZE + s0);
    a0 += pa*dv.x; a1 += pa*dv.y;
  }
  av[(size_t)row*ASIZE + s0] = a0; av[(size_t)row*ASIZE + s0 + 1] = a1;
}

// K10: transfers[row,:] = p_trans[row] @ transfer_dict (64x8192)
__global__ __launch_bounds__(256) void k_trans_mm(const float* __restrict__ p_trans,
                                                   const float* __restrict__ td,
                                                   float* __restrict__ trans) {
  const int row = blockIdx.y;
  const int t = blockIdx.x*2048 + threadIdx.x*8;
  __shared__ float p[NTRANS];
  if (threadIdx.x < NTRANS) p[threadIdx.x] = p_trans[(size_t)row*NTRANS + threadIdx.x];
  __syncthreads();
  float a0=0,a1=0,a2=0,a3=0,a4=0,a5=0,a6=0,a7=0;
  for (int j = 0; j < NTRANS; ++j) {
    const float pj = p[j];
    const float4 v0 = *(const float4*)(td + (size_t)j*TSIZE + t);
    const float4 v1 = *(const float4*)(td + (size_t)j*TSIZE + t + 4);
    a0 += pj*v0.x; a1 += pj*v0.y; a2 += pj*v0.z; a3 += pj*v0.w;
    a4 += pj*v1.x; a5 += pj*v1.y; a6 += pj*v1.z; a7 += pj*v1.w;
  }
  float* o = trans + (size_t)row*TSIZE + t;
  o[0]=a0; o[1]=a1; o[2]=a2; o[3]=a3; o[4]=a4; o[5]=a5; o[6]=a6; o[7]=a7;
}

// K11: ev conv; rolling window with EPAD skew
__global__ __launch_bounds__(256) void k_ev(const float* __restrict__ trans,
                                            const float* __restrict__ av,
                                            const float* __restrict__ amps,
                                            float* __restrict__ ev) {
  const int row = blockIdx.y;
  const int t0 = blockIdx.x * 1024;
  __shared__ float al[512];
  __shared__ float tw[1584];
  for (int i = threadIdx.x; i < 512; i += 256) al[i] = av[(size_t)row*ASIZE + i];
  for (int i = threadIdx.x; i < 1536; i += 256) {
    const int g = t0 - 512 + i;
    tw[EPAD(i)] = (g >= 0) ? trans[(size_t)row*TSIZE + g] : 0.f;
  }
  __syncthreads();
  const int base = threadIdx.x*4 + 512;
  float a0=0,a1=0,a2=0,a3=0;
  float w0=tw[EPAD(base)], w1=tw[EPAD(base+1)], w2=tw[EPAD(base+2)], w3=tw[EPAD(base+3)];
#pragma unroll 8
  for (int k = 0; k < 512; ++k) {
    const float ak = al[k];
    a0 += ak*w0; a1 += ak*w1; a2 += ak*w2; a3 += ak*w3;
    w3 = w2; w2 = w1; w1 = w0;
    const int p = base - k - 1;
    w0 = tw[EPAD(p)];
  }
  const int n = t0 + threadIdx.x*4;
  const float amp = amps[row];
  float* e = ev + (size_t)row*TSIZE + n;
  e[0] = (a0 + (n+0 < 512 ? al[n+0] : 0.f)) * amp;
  e[1] = (a1 + (n+1 < 512 ? al[n+1] : 0.f)) * amp;
  e[2] = (a2 + (n+2 < 512 ? al[n+2] : 0.f)) * amp;
  e[3] = (a3 + (n+3 < 512 ? al[n+3] : 0.f)) * amp;
}

// K12: overlap-add gather, atomics-free; writes dry + reversed-scaled drev.
__global__ __launch_bounds__(256) void k_dry(const float* __restrict__ ev,
                                             const int* __restrict__ idxs,
                                             float* __restrict__ dry,
                                             _Float16* __restrict__ drev) {
  __shared__ int sidx[NROWS];
  if (threadIdx.x < NROWS) sidx[threadIdx.x] = idxs[threadIdx.x];
  __syncthreads();
  const int p = blockIdx.x*256 + threadIdx.x;
  float a = 0.f;
  for (int r = 0; r < NROWS; ++r) {
    const int off = p - sidx[r];
    if ((unsigned)off < TSIZE) a += ev[(size_t)r*TSIZE + off];
  }
  dry[p] = a;
  drev[TSAMP - 1 - p] = (_Float16)(a * DRY_SCALE);
}

// K14: impulse[b,t] -> f16 hi only, ×2^6
__global__ __launch_bounds__(256) void k_impulse(const float* __restrict__ roomp,
                                                 const float* __restrict__ rooms,
                                                 _Float16* __restrict__ ihi) {
  const int b = blockIdx.y;
  const int t = blockIdx.x*1024 + threadIdx.x*4;
  float a0=0,a1=0,a2=0,a3=0;
  for (int r = 0; r < 8; ++r) {
    const float pr = roomp[b*8 + r];
    const float4 v = *(const float4*)(rooms + (size_t)r*TSAMP + t);
    a0 += pr*v.x; a1 += pr*v.y; a2 += pr*v.z; a3 += pr*v.w;
  }
  _Float16* oh = ihi + (size_t)b*TSAMP + t;
  oh[0] = (_Float16)(a0*IMP_SCALE); oh[1] = (_Float16)(a1*IMP_SCALE);
  oh[2] = (_Float16)(a2*IMP_SCALE); oh[3] = (_Float16)(a3*IMP_SCALE);
}

// K15: reverb conv via f16 MFMA (hi-only), N=512/block, k-slab 4096.
__global__ __launch_bounds__(256) void k_wet_mfma(
    const _Float16* __restrict__ drev, const _Float16* __restrict__ ihi,
    float* __restrict__ wet) {
  const int t0 = blockIdx.x * 512;
  const int k0 = blockIdx.y * 4096;
  if (k0 > t0 + 511) return;
  __shared__ _Float16 rhi[8*1048];
  const int tid = threadIdx.x;
  const int wv = tid >> 6;
  const int lane = tid & 63;
  const int n16 = lane & 15;
  const int quad = lane >> 4;
  const int m = n16;

  f32x4 acc[8];
#pragma unroll
  for (int j = 0; j < 8; ++j) acc[j] = (f32x4){0.f,0.f,0.f,0.f};

  const int kend = (k0 + 4096 < t0 + 512) ? k0 + 4096 : t0 + 512;
  const int ph = 7 - (n16 & 7);
  for (int kc0 = k0; kc0 < kend; kc0 += 512) {
    const int RB = TSAMP - 1 - (t0 + 511 - kc0);
    for (int flat = tid; flat < 8*1016; flat += 256) {
      const int p = flat / 1016;
      const int q = flat - p*1016;
      rhi[p*1048 + q] = drev[RB + p + q];
    }
    __syncthreads();

#pragma unroll 4
    for (int kc = 0; kc < 16; ++kc) {
      const int kb = kc*32;
      const int jg = kc0 + kb + quad*8;
      f16x8 ah;
      if (m < NBATCH) ah = *(const f16x8*)(ihi + (size_t)m*TSAMP + jg);
      else ah = (f16x8){0,0,0,0,0,0,0,0};
#pragma unroll
      for (int ts = 0; ts < 8; ++ts) {
        const int nn = wv*128 + ts*16 + n16;
        const int a = ph*1048 + kb + quad*8 + 504 - (nn & ~7);
        const f16x8 bh = *(const f16x8*)(rhi + a);
        acc[ts] = __builtin_amdgcn_mfma_f32_16x16x32_f16(ah, bh, acc[ts], 0, 0, 0);
      }
    }
    __syncthreads();
  }

#pragma unroll
  for (int ts = 0; ts < 8; ++ts) {
    const int t = t0 + wv*128 + ts*16 + n16;
#pragma unroll
    for (int r = 0; r < 4; ++r) {
      const int b = quad*4 + r;
      if (b < NBATCH)
        atomicAdd(wet + (size_t)b*TSAMP + t, acc[ts][r] * WET_DESCALE);
    }
  }
}

// K16: out = dry*(1-mix) + wet*mix
__global__ __launch_bounds__(256) void k_out(const float* __restrict__ dry,
                                             const float* __restrict__ wet,
                                             const float* __restrict__ mix,
                                             float* __restrict__ out) {
  const int b = blockIdx.y;
  const int t = blockIdx.x*1024 + threadIdx.x*4;
  const float m = mix[b];
  const float4 d = *(const float4*)(dry + t);
  const float4 w = *(const float4*)(wet + (size_t)b*TSAMP + t);
  float* o = out + (size_t)b*TSAMP + t;
  o[0] = d.x*(1.f-m) + w.x*m;
  o[1] = d.y*(1.f-m) + w.y*m;
  o[2] = d.z*(1.f-m) + w.z*m;
  o[3] = d.w*(1.f-m) + w.w*m;
}

// ------------------------------------------------------------------
extern "C" void kernel_launch(void* const* d_in, const int* in_sizes, int n_in,
                              void* d_out, int out_size, void* d_ws, size_t ws_size,
                              hipStream_t stream) {
  (void)in_sizes; (void)n_in; (void)out_size; (void)ws_size;
  const float* x      = (const float*)d_in[0];
  const float* bank   = (const float*)d_in[1];
  const float* w_net  = (const float*)d_in[2];
  const float* b_net  = (const float*)d_in[3];
  const float* attn_w = (const float*)d_in[4];
  const float* attn_b = (const float*)d_in[5];
  const float* a_hw = (const float*)d_in[6];
  const float* a_hb = (const float*)d_in[7];
  const float* a_ow = (const float*)d_in[8];
  const float* a_ob = (const float*)d_in[9];
  const float* t_hw = (const float*)d_in[10];
  const float* t_hb = (const float*)d_in[11];
  const float* t_ow = (const float*)d_in[12];
  const float* t_ob = (const float*)d_in[13];
  const float* m_hw = (const float*)d_in[14];
  const float* m_hb = (const float*)d_in[15];
  const float* m_ow = (const float*)d_in[16];
  const float* m_ob = (const float*)d_in[17];
  const float* atoms_dict    = (const float*)d_in[18];
  const float* transfer_dict = (const float*)d_in[19];
  const float* rooms  = (const float*)d_in[20];
  const float* room_w = (const float*)d_in[21];
  const float* room_b = (const float*)d_in[22];
  const float* mix_w  = (const float*)d_in[23];
  const float* mix_b  = (const float*)d_in[24];
  float* out = (float*)d_out;

  // ---- workspace (203.6 MB): H | t1 | t2 | weights | sums/cmax/attnraw
  float* ws = (float*)d_ws;
  const size_t S = (size_t)CCH * TSAMP;        // floats per batch
  float* H  = ws;                               // [B][T][C]
  float* t1 = ws + (size_t)33554432;
  float* t2 = ws + (size_t)41943040;
  _Float16* whi = (_Float16*)(ws + (size_t)50331648);
  _Float16* wlo = whi + 245760;
  _Float16* bhi = wlo + 245760;
  _Float16* blo = bhi + 65536;
  double* sums    = (double*)(ws + (size_t)50642944);   // 16 doubles
  unsigned* cmax  = (unsigned*)(ws + (size_t)50642976); // 8*128 uints
  float* attnraw  = ws + (size_t)50644000;              // 8*32768

  size_t off = 33554432;                       // scratch base (aliases t1)
  float* scal  = ws + off; off += 8;
  float* vals  = ws + off; off += NROWS;
  int*   idxs  = (int*)(ws + off); off += NROWS;
  float* p_atoms = ws + off; off += (size_t)NROWS*NATOMS;
  float* p_trans = ws + off; off += (size_t)NROWS*NTRANS;
  float* amps  = ws + off; off += NROWS;
  float* av    = ws + off; off += (size_t)NROWS*ASIZE;
  float* trans = ws + off; off += (size_t)NROWS*TSIZE;
  float* ev    = ws + off; off += (size_t)NROWS*TSIZE;
  float* dry   = ws + off; off += TSAMP;
  float* roomp = ws + off; off += 64;
  float* mix   = ws + off; off += 8;
  float* wet   = ws + off; off += (size_t)NBATCH*TSAMP;
  float* cand_v = ws + off; off += 4096;
  int*   cand_i = (int*)(ws + off); off += 4096;
  _Float16* imphi = (_Float16*)(ws + off); off += (size_t)NBATCH*TSAMP/2;
  _Float16* drev  = (_Float16*)(ws + off); off += (TSAMP + 1088)/2 + 4;

  k_prep<<<1216, 256, 0, stream>>>(w_net, bank, whi, wlo, bhi, blo, sums, cmax);
  k_front_mfma<<<dim3(256, 8), 256, 0, stream>>>(x, bhi, blo, H);

  const int dil[5] = {1, 3, 9, 27, 1};
  for (int p = 0; p < 4; ++p) {            // 2 batches per dispatch
    float* Hp = H + (size_t)(2*p) * S;
    float* io[6] = {Hp, t1, t2, t1, t2, Hp};
    for (int i = 0; i < 3; ++i) {          // d = 1, 3, 9: 128-t tiles
      const int d = dil[i];
      const size_t smem = (size_t)(128 + 2*d) * 544;
      k_dil128<<<dim3(256, 2), 256, smem, stream>>>(
          io[i], whi + (size_t)i*49152, wlo + (size_t)i*49152, b_net + i*CCH,
          io[i+1], d);
    }
    {                                      // d = 27: 80-t tiles
      const size_t smem = (size_t)134 * 544;
      k_dil80<<<dim3(410, 2), 256, smem, stream>>>(
          io[3], whi + (size_t)3*49152, wlo + (size_t)3*49152, b_net + 3*CCH,
          io[4]);
    }
    {                                      // last layer d=1: fused epilogue
      const int d = dil[4];
      const size_t smem = (size_t)(128 + 2*d) * 544;
      k_dil_last<<<dim3(256, 2), 256, smem, stream>>>(
          io[4], whi + (size_t)4*49152, wlo + (size_t)4*49152, b_net + 4*CCH,
          io[5], d, attn_w, sums, attnraw, cmax, 2*p);
    }
  }

  k_zero<<<1024, 256, 0, stream>>>(wet, drev);
  k_finish<<<8, 128, 0, stream>>>(sums, cmax, room_w, room_b, mix_w, mix_b,
                                  scal, roomp, mix);
  k_topk1<<<dim3(16, 8), 256, 0, stream>>>(attnraw, scal, attn_b, cand_v, cand_i);
  k_topk2<<<8, 512, 0, stream>>>(cand_v, cand_i, vals, idxs);
  k_mlp<<<256, 128, 0, stream>>>(H, scal, vals, idxs,
                                 a_hw, a_hb, a_ow, a_ob,
                                 t_hw, t_hb, t_ow, t_ob,
                                 m_hw, m_hb, m_ow, m_ob,
                                 p_atoms, p_trans, amps);
  k_atoms_mm<<<256, 256, 0, stream>>>(p_atoms, atoms_dict, av);
  k_trans_mm<<<dim3(4, 256), 256, 0, stream>>>(p_trans, transfer_dict, trans);
  k_ev<<<dim3(8, 256), 256, 0, stream>>>(trans, av, amps, ev);
  k_dry<<<128, 256, 0, stream>>>(ev, idxs, dry, drev);
  k_impulse<<<dim3(32, 8), 256, 0, stream>>>(roomp, rooms, imphi);
  k_wet_mfma<<<dim3(64, 8), 256, 0, stream>>>(drev, imphi, wet);
  k_out<<<dim3(32, 8), 256, 0, stream>>>(dry, wet, mix, out);
}

// Round 13
// 1263.306 us; speedup vs baseline: 1.2800x; 1.2800x over previous
//
#include <hip/hip_runtime.h>
#include <math.h>

#define TSAMP 32768
#define CCH 128
#define NBATCH 8
#define NEV 32
#define NROWS 256   // NBATCH*NEV
#define NATOMS 512
#define ASIZE 512
#define NTRANS 64
#define TSIZE 8192

#define DRY_SCALE 16777216.0f               // 2^24
#define IMP_SCALE 64.0f                     // 2^6
#define WET_DESCALE 9.313225746154785e-10f  // 2^-30

// LDS skew for stride-4 lane patterns: 8-way conflict -> 2-way (free)
#define EPAD(i) ((i) + ((i) >> 5))

typedef _Float16 f16x8 __attribute__((ext_vector_type(8)));
typedef _Float16 f16x4 __attribute__((ext_vector_type(4)));
typedef float f32x4 __attribute__((ext_vector_type(4)));

// activations stored [B][T][C] (c contiguous).

// ------------------------------------------------------------------
// K-prep: split conv weights ([layer][k][o][ci]) + filter bank ([c][k]) to
// f16 hi/lo, and zero the f64 stat sums. One dispatch.
__global__ __launch_bounds__(256) void k_prep(const float* __restrict__ wn,
                                              const float* __restrict__ bank,
                                              _Float16* __restrict__ whi,
                                              _Float16* __restrict__ wlo,
                                              _Float16* __restrict__ bhi,
                                              _Float16* __restrict__ blo,
                                              double* __restrict__ sums) {
  const int i = blockIdx.x * 256 + threadIdx.x;
  if (i < 16) sums[i] = 0.0;
  if (i < 245760) {
    const int ci = i & 127;
    int r = i >> 7;
    const int o = r & 127;
    r >>= 7;
    const int k = r % 3;
    const int l = r / 3;
    const float w = wn[(((size_t)l*128 + o)*128 + ci)*3 + k];
    const _Float16 hi = (_Float16)w;
    whi[i] = hi;
    wlo[i] = (_Float16)(w - (float)hi);
  } else if (i < 311296) {
    const int j = i - 245760;
    const float w = bank[j];
    const _Float16 hi = (_Float16)w;
    bhi[j] = hi;
    blo[j] = (_Float16)(w - (float)hi);
  }
}

// K0: zero wet accumulator + drev zero-pad tail
__global__ __launch_bounds__(256) void k_zero(float* __restrict__ wet,
                                              _Float16* __restrict__ drev) {
  int i = blockIdx.x * 256 + threadIdx.x;
  if (i < NBATCH * TSAMP) wet[i] = 0.f;
  if (i < 1088) drev[TSAMP + i] = (_Float16)0.f;
}

// ------------------------------------------------------------------
// K1: front filter bank via split-f16 MFMA, 128-t blocks (8 ts tiles/wave).
// (R11-proven tiling: 32c/wave, hoisted A-fragments, deep ts.)
__global__ __launch_bounds__(256) void k_front_mfma(
    const float* __restrict__ x, const _Float16* __restrict__ bhi,
    const _Float16* __restrict__ blo, float* __restrict__ h) {
  __shared__ _Float16 shi[8*664];
  __shared__ _Float16 slo[8*664];
  const int t0 = blockIdx.x * 128;
  const int b  = blockIdx.y;
  const float* xb = x + (size_t)b*TSAMP;
  const int tid = threadIdx.x;

  for (int flat = tid; flat < 8*632; flat += 256) {
    const int p = flat / 632;
    const int q = flat - p*632;
    const int g = t0 - 256 + q + p;
    const float v = (g >= 0 && g < TSAMP) ? xb[g] : 0.f;
    const _Float16 hi = (_Float16)v;
    shi[p*664 + q] = hi;
    slo[p*664 + q] = (_Float16)(v - (float)hi);
  }
  __syncthreads();

  const int wv = tid >> 6;
  const int lane = tid & 63;
  const int n = lane & 15;
  const int quad = lane >> 4;
  const int c0 = wv * 32;
  const int ph = n & 7;
  const int nb = n & 8;

  f32x4 acc[2][8];
#pragma unroll
  for (int i = 0; i < 2; ++i)
#pragma unroll
    for (int j = 0; j < 8; ++j) acc[i][j] = (f32x4){0.f,0.f,0.f,0.f};

  for (int kc = 0; kc < 16; ++kc) {
    const int kb = kc*32 + quad*8;
    f16x8 ahi[2], alo[2];
#pragma unroll
    for (int os = 0; os < 2; ++os) {
      const size_t ao = (size_t)(c0 + os*16 + n)*512 + kb;
      ahi[os] = *(const f16x8*)(bhi + ao);
      alo[os] = *(const f16x8*)(blo + ao);
    }
#pragma unroll
    for (int tg = 0; tg < 2; ++tg) {
      f16x8 xh[4], xl[4];
#pragma unroll
      for (int u = 0; u < 4; ++u) {
        const int a = ph*664 + (tg*4 + u)*16 + nb + kb;
        xh[u] = *(const f16x8*)(shi + a);
        xl[u] = *(const f16x8*)(slo + a);
      }
#pragma unroll
      for (int os = 0; os < 2; ++os)
#pragma unroll
        for (int u = 0; u < 4; ++u) {
          f32x4 a4 = acc[os][tg*4 + u];
          a4 = __builtin_amdgcn_mfma_f32_16x16x32_f16(ahi[os], xh[u], a4, 0, 0, 0);
          a4 = __builtin_amdgcn_mfma_f32_16x16x32_f16(alo[os], xh[u], a4, 0, 0, 0);
          a4 = __builtin_amdgcn_mfma_f32_16x16x32_f16(ahi[os], xl[u], a4, 0, 0, 0);
          acc[os][tg*4 + u] = a4;
        }
    }
  }

  float* hb = h + (size_t)b*TSAMP*CCH;
#pragma unroll
  for (int os = 0; os < 2; ++os) {
    const int cb = c0 + os*16 + quad*4;
#pragma unroll
    for (int ts = 0; ts < 8; ++ts) {
      const int t = t0 + ts*16 + n;
      *(f32x4*)(hb + (size_t)t*CCH + cb) = acc[os][ts];
    }
  }
}

// ------------------------------------------------------------------
// K2a: 80-t dilated conv layer for d=27 (LDS 72.9 KB -> 2 blocks/CU).
__global__ __launch_bounds__(256) void k_dil80(
    const float* __restrict__ hin0, const _Float16* __restrict__ whi,
    const _Float16* __restrict__ wlo, const float* __restrict__ bias,
    float* __restrict__ hout0) {
  const int d = 27;
  extern __shared__ _Float16 sh[];
  const int twin = 80 + 2*d;              // 134
  _Float16* shi = sh;
  _Float16* slo = sh + twin*136;
  const int t0 = blockIdx.x * 80;
  const size_t bs = (size_t)blockIdx.y * CCH * TSAMP;
  const float* __restrict__ hin = hin0 + bs;
  float* __restrict__ hout = hout0 + bs;
  const int tid = threadIdx.x;

  for (int flat = tid; flat < twin*32; flat += 256) {
    const int tw = flat >> 5;
    const int c4 = (flat & 31) << 2;
    const int g = t0 - d + tw;
    float4 v = {0.f, 0.f, 0.f, 0.f};
    if (g >= 0 && g < TSAMP) v = *(const float4*)(hin + (size_t)g*CCH + c4);
    f16x4 hv, lv;
    hv[0] = (_Float16)v.x; hv[1] = (_Float16)v.y;
    hv[2] = (_Float16)v.z; hv[3] = (_Float16)v.w;
    lv[0] = (_Float16)(v.x - (float)hv[0]); lv[1] = (_Float16)(v.y - (float)hv[1]);
    lv[2] = (_Float16)(v.z - (float)hv[2]); lv[3] = (_Float16)(v.w - (float)hv[3]);
    *(f16x4*)(shi + tw*136 + c4) = hv;
    *(f16x4*)(slo + tw*136 + c4) = lv;
  }
  __syncthreads();

  const int wv = tid >> 6;
  const int lane = tid & 63;
  const int n = lane & 15;
  const int quad = lane >> 4;
  const int o0 = wv * 32;

  f32x4 acc[2][5];
#pragma unroll
  for (int i = 0; i < 2; ++i)
#pragma unroll
    for (int j = 0; j < 5; ++j) acc[i][j] = (f32x4){0.f,0.f,0.f,0.f};

  for (int k = 0; k < 3; ++k) {
    for (int kc = 0; kc < 4; ++kc) {
      const int cib = kc*32 + quad*8;
      f16x8 ahi[2], alo[2];
#pragma unroll
      for (int os = 0; os < 2; ++os) {
        const size_t wo = ((size_t)k*128 + (o0 + os*16 + n))*128 + cib;
        ahi[os] = *(const f16x8*)(whi + wo);
        alo[os] = *(const f16x8*)(wlo + wo);
      }
      f16x8 bh[5], bl[5];
#pragma unroll
      for (int ts = 0; ts < 5; ++ts) {
        const int a = (ts*16 + n + k*d)*136 + cib;
        bh[ts] = *(const f16x8*)(shi + a);
        bl[ts] = *(const f16x8*)(slo + a);
      }
#pragma unroll
      for (int os = 0; os < 2; ++os)
#pragma unroll
        for (int ts = 0; ts < 5; ++ts) {
          acc[os][ts] = __builtin_amdgcn_mfma_f32_16x16x32_f16(ahi[os], bh[ts], acc[os][ts], 0, 0, 0);
          acc[os][ts] = __builtin_amdgcn_mfma_f32_16x16x32_f16(alo[os], bh[ts], acc[os][ts], 0, 0, 0);
          acc[os][ts] = __builtin_amdgcn_mfma_f32_16x16x32_f16(ahi[os], bl[ts], acc[os][ts], 0, 0, 0);
        }
    }
  }

#pragma unroll
  for (int os = 0; os < 2; ++os) {
    const int ob = o0 + os*16 + quad*4;
    const f32x4 bs4 = *(const f32x4*)(bias + ob);
#pragma unroll
    for (int ts = 0; ts < 5; ++ts) {
      const int t = t0 + ts*16 + n;
      if (t < TSAMP) {
        const int tw = ts*16 + n + d;
        const f16x4 phv = *(const f16x4*)(shi + tw*136 + ob);
        const f16x4 plv = *(const f16x4*)(slo + tw*136 + ob);
        f32x4 res;
#pragma unroll
        for (int r = 0; r < 4; ++r) {
          float v = acc[os][ts][r] + bs4[r];
          v = v > 0.f ? v : 0.2f*v;
          res[r] = (float)phv[r] + (float)plv[r] + v;
        }
        *(f32x4*)(hout + (size_t)t*CCH + ob) = res;
      }
    }
  }
}

// ------------------------------------------------------------------
// K2b: 128-t dilated conv layer (d=3,9): 576 MFMA/wave, 8 acc chains.
__global__ __launch_bounds__(256) void k_dil128(
    const float* __restrict__ hin0, const _Float16* __restrict__ whi,
    const _Float16* __restrict__ wlo, const float* __restrict__ bias,
    float* __restrict__ hout0, const int d) {
  extern __shared__ _Float16 sh[];
  const int twin = 128 + 2*d;
  _Float16* shi = sh;
  _Float16* slo = sh + twin*136;
  const int t0 = blockIdx.x * 128;
  const size_t bs = (size_t)blockIdx.y * CCH * TSAMP;
  const float* __restrict__ hin = hin0 + bs;
  float* __restrict__ hout = hout0 + bs;
  const int tid = threadIdx.x;

  for (int flat = tid; flat < twin*32; flat += 256) {
    const int tw = flat >> 5;
    const int c4 = (flat & 31) << 2;
    const int g = t0 - d + tw;
    float4 v = {0.f, 0.f, 0.f, 0.f};
    if (g >= 0 && g < TSAMP) v = *(const float4*)(hin + (size_t)g*CCH + c4);
    f16x4 hv, lv;
    hv[0] = (_Float16)v.x; hv[1] = (_Float16)v.y;
    hv[2] = (_Float16)v.z; hv[3] = (_Float16)v.w;
    lv[0] = (_Float16)(v.x - (float)hv[0]); lv[1] = (_Float16)(v.y - (float)hv[1]);
    lv[2] = (_Float16)(v.z - (float)hv[2]); lv[3] = (_Float16)(v.w - (float)hv[3]);
    *(f16x4*)(shi + tw*136 + c4) = hv;
    *(f16x4*)(slo + tw*136 + c4) = lv;
  }
  __syncthreads();

  const int wv = tid >> 6;
  const int lane = tid & 63;
  const int n = lane & 15;
  const int quad = lane >> 4;
  const int o0 = wv * 32;

  f32x4 acc[2][8];
#pragma unroll
  for (int i = 0; i < 2; ++i)
#pragma unroll
    for (int j = 0; j < 8; ++j) acc[i][j] = (f32x4){0.f,0.f,0.f,0.f};

  for (int k = 0; k < 3; ++k) {
    for (int kc = 0; kc < 4; ++kc) {
      const int cib = kc*32 + quad*8;
      f16x8 ahi[2], alo[2];
#pragma unroll
      for (int os = 0; os < 2; ++os) {
        const size_t wo = ((size_t)k*128 + (o0 + os*16 + n))*128 + cib;
        ahi[os] = *(const f16x8*)(whi + wo);
        alo[os] = *(const f16x8*)(wlo + wo);
      }
#pragma unroll
      for (int tg = 0; tg < 2; ++tg) {
        f16x8 bh[4], bl[4];
#pragma unroll
        for (int u = 0; u < 4; ++u) {
          const int a = ((tg*4 + u)*16 + n + k*d)*136 + cib;
          bh[u] = *(const f16x8*)(shi + a);
          bl[u] = *(const f16x8*)(slo + a);
        }
#pragma unroll
        for (int os = 0; os < 2; ++os)
#pragma unroll
          for (int u = 0; u < 4; ++u) {
            f32x4 a4 = acc[os][tg*4 + u];
            a4 = __builtin_amdgcn_mfma_f32_16x16x32_f16(ahi[os], bh[u], a4, 0, 0, 0);
            a4 = __builtin_amdgcn_mfma_f32_16x16x32_f16(alo[os], bh[u], a4, 0, 0, 0);
            a4 = __builtin_amdgcn_mfma_f32_16x16x32_f16(ahi[os], bl[u], a4, 0, 0, 0);
            acc[os][tg*4 + u] = a4;
          }
      }
    }
  }

#pragma unroll
  for (int os = 0; os < 2; ++os) {
    const int ob = o0 + os*16 + quad*4;
    const f32x4 bs4 = *(const f32x4*)(bias + ob);
#pragma unroll
    for (int ts = 0; ts < 8; ++ts) {
      const int t = t0 + ts*16 + n;
      const int tw = ts*16 + n + d;
      const f16x4 phv = *(const f16x4*)(shi + tw*136 + ob);
      const f16x4 plv = *(const f16x4*)(slo + tw*136 + ob);
      f32x4 res;
#pragma unroll
      for (int r = 0; r < 4; ++r) {
        float v = acc[os][ts][r] + bs4[r];
        v = v > 0.f ? v : 0.2f*v;
        res[r] = (float)phv[r] + (float)plv[r] + v;
      }
      *(f32x4*)(hout + (size_t)t*CCH + ob) = res;
    }
  }
}

// ------------------------------------------------------------------
// K2b96: 96-t dilated conv for d=1 (layer 0): LDS 53.3 KB -> 3 blocks/CU.
// Same MFMA order per output as k_dil128 (bit-identical numerics).
__global__ __launch_bounds__(256) void k_dil96(
    const float* __restrict__ hin0, const _Float16* __restrict__ whi,
    const _Float16* __restrict__ wlo, const float* __restrict__ bias,
    float* __restrict__ hout0, const int d) {
  extern __shared__ _Float16 sh[];
  const int twin = 96 + 2*d;
  _Float16* shi = sh;
  _Float16* slo = sh + twin*136;
  const int t0 = blockIdx.x * 96;
  const size_t bs = (size_t)blockIdx.y * CCH * TSAMP;
  const float* __restrict__ hin = hin0 + bs;
  float* __restrict__ hout = hout0 + bs;
  const int tid = threadIdx.x;

  for (int flat = tid; flat < twin*32; flat += 256) {
    const int tw = flat >> 5;
    const int c4 = (flat & 31) << 2;
    const int g = t0 - d + tw;
    float4 v = {0.f, 0.f, 0.f, 0.f};
    if (g >= 0 && g < TSAMP) v = *(const float4*)(hin + (size_t)g*CCH + c4);
    f16x4 hv, lv;
    hv[0] = (_Float16)v.x; hv[1] = (_Float16)v.y;
    hv[2] = (_Float16)v.z; hv[3] = (_Float16)v.w;
    lv[0] = (_Float16)(v.x - (float)hv[0]); lv[1] = (_Float16)(v.y - (float)hv[1]);
    lv[2] = (_Float16)(v.z - (float)hv[2]); lv[3] = (_Float16)(v.w - (float)hv[3]);
    *(f16x4*)(shi + tw*136 + c4) = hv;
    *(f16x4*)(slo + tw*136 + c4) = lv;
  }
  __syncthreads();

  const int wv = tid >> 6;
  const int lane = tid & 63;
  const int n = lane & 15;
  const int quad = lane >> 4;
  const int o0 = wv * 32;

  f32x4 acc[2][6];
#pragma unroll
  for (int i = 0; i < 2; ++i)
#pragma unroll
    for (int j = 0; j < 6; ++j) acc[i][j] = (f32x4){0.f,0.f,0.f,0.f};

  for (int k = 0; k < 3; ++k) {
    for (int kc = 0; kc < 4; ++kc) {
      const int cib = kc*32 + quad*8;
      f16x8 ahi[2], alo[2];
#pragma unroll
      for (int os = 0; os < 2; ++os) {
        const size_t wo = ((size_t)k*128 + (o0 + os*16 + n))*128 + cib;
        ahi[os] = *(const f16x8*)(whi + wo);
        alo[os] = *(const f16x8*)(wlo + wo);
      }
      f16x8 bh[6], bl[6];
#pragma unroll
      for (int u = 0; u < 6; ++u) {
        const int a = (u*16 + n + k*d)*136 + cib;
        bh[u] = *(const f16x8*)(shi + a);
        bl[u] = *(const f16x8*)(slo + a);
      }
#pragma unroll
      for (int os = 0; os < 2; ++os)
#pragma unroll
        for (int u = 0; u < 6; ++u) {
          f32x4 a4 = acc[os][u];
          a4 = __builtin_amdgcn_mfma_f32_16x16x32_f16(ahi[os], bh[u], a4, 0, 0, 0);
          a4 = __builtin_amdgcn_mfma_f32_16x16x32_f16(alo[os], bh[u], a4, 0, 0, 0);
          a4 = __builtin_amdgcn_mfma_f32_16x16x32_f16(ahi[os], bl[u], a4, 0, 0, 0);
          acc[os][u] = a4;
        }
    }
  }

#pragma unroll
  for (int os = 0; os < 2; ++os) {
    const int ob = o0 + os*16 + quad*4;
    const f32x4 bs4 = *(const f32x4*)(bias + ob);
#pragma unroll
    for (int ts = 0; ts < 6; ++ts) {
      const int t = t0 + ts*16 + n;
      if (t < TSAMP) {
        const int tw = ts*16 + n + d;
        const f16x4 phv = *(const f16x4*)(shi + tw*136 + ob);
        const f16x4 plv = *(const f16x4*)(slo + tw*136 + ob);
        f32x4 res;
#pragma unroll
        for (int r = 0; r < 4; ++r) {
          float v = acc[os][ts][r] + bs4[r];
          v = v > 0.f ? v : 0.2f*v;
          res[r] = (float)phv[r] + (float)plv[r] + v;
        }
        *(f32x4*)(hout + (size_t)t*CCH + ob) = res;
      }
    }
  }
}

// ------------------------------------------------------------------
// K2c: LAST layer (d=1), 128-t, with fused stats/attn/context epilogue.
__global__ __launch_bounds__(256) void k_dil_last(
    const float* __restrict__ hin0, const _Float16* __restrict__ whi,
    const _Float16* __restrict__ wlo, const float* __restrict__ bias,
    float* __restrict__ hout0, const int d,
    const float* __restrict__ aw, double* __restrict__ sums,
    float* __restrict__ attnraw, float* __restrict__ pm, const int bb0) {
  extern __shared__ _Float16 sh[];
  const int twin = 128 + 2*d;
  _Float16* shi = sh;
  _Float16* slo = sh + twin*136;
  __shared__ float attl[4*128];
  __shared__ double sred[8];
  const int t0 = blockIdx.x * 128;
  const int b = bb0 + blockIdx.y;
  const size_t bs = (size_t)blockIdx.y * CCH * TSAMP;
  const float* __restrict__ hin = hin0 + bs;
  float* __restrict__ hout = hout0 + bs;
  const int tid = threadIdx.x;

  for (int flat = tid; flat < twin*32; flat += 256) {
    const int tw = flat >> 5;
    const int c4 = (flat & 31) << 2;
    const int g = t0 - d + tw;
    float4 v = {0.f, 0.f, 0.f, 0.f};
    if (g >= 0 && g < TSAMP) v = *(const float4*)(hin + (size_t)g*CCH + c4);
    f16x4 hv, lv;
    hv[0] = (_Float16)v.x; hv[1] = (_Float16)v.y;
    hv[2] = (_Float16)v.z; hv[3] = (_Float16)v.w;
    lv[0] = (_Float16)(v.x - (float)hv[0]); lv[1] = (_Float16)(v.y - (float)hv[1]);
    lv[2] = (_Float16)(v.z - (float)hv[2]); lv[3] = (_Float16)(v.w - (float)hv[3]);
    *(f16x4*)(shi + tw*136 + c4) = hv;
    *(f16x4*)(slo + tw*136 + c4) = lv;
  }
  __syncthreads();

  const int wv = tid >> 6;
  const int lane = tid & 63;
  const int n = lane & 15;
  const int quad = lane >> 4;
  const int o0 = wv * 32;

  f32x4 acc[2][8];
#pragma unroll
  for (int i = 0; i < 2; ++i)
#pragma unroll
    for (int j = 0; j < 8; ++j) acc[i][j] = (f32x4){0.f,0.f,0.f,0.f};

  for (int k = 0; k < 3; ++k) {
    for (int kc = 0; kc < 4; ++kc) {
      const int cib = kc*32 + quad*8;
      f16x8 ahi[2], alo[2];
#pragma unroll
      for (int os = 0; os < 2; ++os) {
        const size_t wo = ((size_t)k*128 + (o0 + os*16 + n))*128 + cib;
        ahi[os] = *(const f16x8*)(whi + wo);
        alo[os] = *(const f16x8*)(wlo + wo);
      }
#pragma unroll
      for (int tg = 0; tg < 2; ++tg) {
        f16x8 bh[4], bl[4];
#pragma unroll
        for (int u = 0; u < 4; ++u) {
          const int a = ((tg*4 + u)*16 + n + k*d)*136 + cib;
          bh[u] = *(const f16x8*)(shi + a);
          bl[u] = *(const f16x8*)(slo + a);
        }
#pragma unroll
        for (int os = 0; os < 2; ++os)
#pragma unroll
          for (int u = 0; u < 4; ++u) {
            f32x4 a4 = acc[os][tg*4 + u];
            a4 = __builtin_amdgcn_mfma_f32_16x16x32_f16(ahi[os], bh[u], a4, 0, 0, 0);
            a4 = __builtin_amdgcn_mfma_f32_16x16x32_f16(alo[os], bh[u], a4, 0, 0, 0);
            a4 = __builtin_amdgcn_mfma_f32_16x16x32_f16(ahi[os], bl[u], a4, 0, 0, 0);
            acc[os][tg*4 + u] = a4;
          }
      }
    }
  }

  const f32x4 awq0 = *(const f32x4*)(aw + o0 + quad*4);
  const f32x4 awq1 = *(const f32x4*)(aw + o0 + 16 + quad*4);
  double s = 0.0, s2 = 0.0;
  float pa[8] = {0.f,0.f,0.f,0.f,0.f,0.f,0.f,0.f};
  f32x4 cm[2];
  cm[0] = (f32x4){-3.4e38f, -3.4e38f, -3.4e38f, -3.4e38f};
  cm[1] = cm[0];

#pragma unroll
  for (int os = 0; os < 2; ++os) {
    const int ob = o0 + os*16 + quad*4;
    const f32x4 bs4 = *(const f32x4*)(bias + ob);
    const f32x4 awv = os ? awq1 : awq0;
#pragma unroll
    for (int ts = 0; ts < 8; ++ts) {
      const int t = t0 + ts*16 + n;
      const int tw = ts*16 + n + d;
      const f16x4 phv = *(const f16x4*)(shi + tw*136 + ob);
      const f16x4 plv = *(const f16x4*)(slo + tw*136 + ob);
      f32x4 res;
      float dotp = 0.f;
#pragma unroll
      for (int r = 0; r < 4; ++r) {
        float v = acc[os][ts][r] + bs4[r];
        v = v > 0.f ? v : 0.2f*v;
        const float hv = (float)phv[r] + (float)plv[r] + v;
        res[r] = hv;
        s += (double)hv; s2 += (double)hv*(double)hv;
        dotp += hv * awv[r];
        cm[os][r] = fmaxf(cm[os][r], hv);
      }
      pa[ts] += dotp;
      *(f32x4*)(hout + (size_t)t*CCH + ob) = res;
    }
  }

#pragma unroll
  for (int ts = 0; ts < 8; ++ts) {
    pa[ts] += __shfl_xor(pa[ts], 16);
    pa[ts] += __shfl_xor(pa[ts], 32);
  }
  if (quad == 0) {
#pragma unroll
    for (int ts = 0; ts < 8; ++ts) attl[wv*128 + ts*16 + n] = pa[ts];
  }
#pragma unroll
  for (int mk = 1; mk <= 8; mk <<= 1)
#pragma unroll
    for (int os = 0; os < 2; ++os)
#pragma unroll
      for (int r = 0; r < 4; ++r)
        cm[os][r] = fmaxf(cm[os][r], __shfl_xor(cm[os][r], mk));
  if (n == 0) {
#pragma unroll
    for (int os = 0; os < 2; ++os)
      *(f32x4*)(pm + ((size_t)b*256 + blockIdx.x)*128 + o0 + os*16 + quad*4) = cm[os];
  }
  for (int sft = 32; sft; sft >>= 1) { s += __shfl_down(s, sft); s2 += __shfl_down(s2, sft); }
  if (lane == 0) { sred[wv*2] = s; sred[wv*2+1] = s2; }
  __syncthreads();
  if (tid < 128)
    attnraw[(size_t)b*TSAMP + t0 + tid] =
        attl[tid] + attl[128 + tid] + attl[256 + tid] + attl[384 + tid];
  if (tid == 0) {
    atomicAdd(&sums[b*2],   sred[0] + sred[2] + sred[4] + sred[6]);
    atomicAdd(&sums[b*2+1], sred[1] + sred[3] + sred[5] + sred[7]);
  }
}

// ------------------------------------------------------------------
// K-finish: per-batch scale + context (LDS only) + room softmax + mix.
__global__ __launch_bounds__(128) void k_finish(
    const double* __restrict__ sums, const float* __restrict__ pm,
    const float* __restrict__ room_w, const float* __restrict__ room_b,
    const float* __restrict__ mix_w, const float* __restrict__ mix_b,
    float* __restrict__ scal, float* __restrict__ roomp, float* __restrict__ mix) {
  const int b = blockIdx.x;
  const int tid = threadIdx.x;
  __shared__ float bs;
  __shared__ float ctx[128];
  if (tid == 0) {
    const double nn = (double)CCH * (double)TSAMP;
    const double mean = sums[b*2] / nn;
    double var = sums[b*2+1] / nn - mean*mean;
    if (var < 0.0) var = 0.0;
    const float sc = (float)(1.0 / (sqrt(var) + 1e-8));
    bs = sc;
    scal[b] = sc;
  }
  __syncthreads();
  float m = -3.4e38f;
  for (int s = 0; s < 256; ++s) m = fmaxf(m, pm[((size_t)b*256 + s)*128 + tid]);
  ctx[tid] = m * bs;
  __syncthreads();
  if (tid < 8) {
    const int r = tid;
    float acc = room_b[r];
    for (int c = 0; c < CCH; ++c) acc += ctx[c] * room_w[c*8 + r];
    float mm = acc;
    for (int s = 1; s < 8; s <<= 1) mm = fmaxf(mm, __shfl_xor(mm, s, 8));
    const float e = expf(acc - mm);
    float ss = e;
    for (int s = 1; s < 8; s <<= 1) ss += __shfl_xor(ss, s, 8);
    roomp[b*8 + r] = e / ss;
  } else if (tid == 8) {
    float a = mix_b[0];
    for (int c = 0; c < CCH; ++c) a += ctx[c] * mix_w[c];
    mix[b] = 1.f/(1.f+expf(-a));
  }
}

// ------------------------------------------------------------------
// K7a: per-2048-chunk top-32 (sigmoid fused into staging).
__global__ __launch_bounds__(256) void k_topk1(const float* __restrict__ raw,
                                               const float* __restrict__ scal,
                                               const float* __restrict__ ab,
                                               float* __restrict__ cv,
                                               int* __restrict__ cidx) {
  const int ch = blockIdx.x, b = blockIdx.y;
  const float sc = scal[b], bb_ = ab[0];
  const float* a = raw + (size_t)b*TSAMP + ch*2048;
  __shared__ float v[2048];
  __shared__ float rv[4]; __shared__ int ri[4];
  const int tid = threadIdx.x;
  for (int i = tid; i < 2048; i += 256)
    v[i] = 1.f/(1.f+expf(-(a[i]*sc + bb_)));
  __syncthreads();
  for (int e = 0; e < NEV; ++e) {
    float bv = -1e30f; int bi = 0;
    for (int i = tid; i < 2048; i += 256) {
      const float x = v[i];
      if (x > bv) { bv = x; bi = i; }
    }
    for (int s = 32; s; s >>= 1) {
      const float ov = __shfl_down(bv, s); const int oi = __shfl_down(bi, s);
      if (ov > bv || (ov == bv && oi < bi)) { bv = ov; bi = oi; }
    }
    if ((tid & 63) == 0) { rv[tid >> 6] = bv; ri[tid >> 6] = bi; }
    __syncthreads();
    if (tid == 0) {
      int bb = 0;
      for (int w2 = 1; w2 < 4; ++w2)
        if (rv[w2] > rv[bb] || (rv[w2] == rv[bb] && ri[w2] < ri[bb])) bb = w2;
      cv[(b*16 + ch)*NEV + e] = rv[bb];
      cidx[(b*16 + ch)*NEV + e] = ch*2048 + ri[bb];
      v[ri[bb]] = -1e30f;
    }
    __syncthreads();
  }
}

// K7b: final top-32 over 512 candidates
__global__ __launch_bounds__(512) void k_topk2(const float* __restrict__ cv,
                                               const int* __restrict__ ci_,
                                               float* __restrict__ vals,
                                               int* __restrict__ idxs) {
  const int b = blockIdx.x;
  const int tid = threadIdx.x;
  float my = cv[b*512 + tid];
  int   mi = ci_[b*512 + tid];
  __shared__ float rv[8]; __shared__ int ri[8];
  __shared__ float bvs; __shared__ int bis;
  for (int e = 0; e < NEV; ++e) {
    float bv = my; int bi = mi;
    for (int s = 32; s; s >>= 1) {
      const float ov = __shfl_down(bv, s); const int oi = __shfl_down(bi, s);
      if (ov > bv || (ov == bv && oi < bi)) { bv = ov; bi = oi; }
    }
    if ((tid & 63) == 0) { rv[tid >> 6] = bv; ri[tid >> 6] = bi; }
    __syncthreads();
    if (tid == 0) {
      int bb = 0;
      for (int w2 = 1; w2 < 8; ++w2)
        if (rv[w2] > rv[bb] || (rv[w2] == rv[bb] && ri[w2] < ri[bb])) bb = w2;
      vals[b*NEV + e] = rv[bb]; idxs[b*NEV + e] = ri[bb];
      bvs = rv[bb]; bis = ri[bb];
    }
    __syncthreads();
    if (mi == bis && my == bvs) my = -1e30f;
    __syncthreads();
  }
}

// ------------------------------------------------------------------
__device__ __forceinline__ float blk_max128(float v, float* red) {
  const int tid = threadIdx.x;
  red[tid] = v; __syncthreads();
  for (int s = 64; s > 0; s >>= 1) {
    if (tid < s) red[tid] = fmaxf(red[tid], red[tid + s]);
    __syncthreads();
  }
  const float r = red[0]; __syncthreads();
  return r;
}
__device__ __forceinline__ float blk_sum128(float v, float* red) {
  const int tid = threadIdx.x;
  red[tid] = v; __syncthreads();
  for (int s = 64; s > 0; s >>= 1) {
    if (tid < s) red[tid] += red[tid + s];
    __syncthreads();
  }
  const float r = red[0]; __syncthreads();
  return r;
}
__device__ __forceinline__ float mlp_hidden3(float latv, const float* __restrict__ hw,
                                             const float* __restrict__ hb, float* xa) {
  const int tid = threadIdx.x;
  float cur = latv;
  for (int i = 0; i < 3; ++i) {
    xa[tid] = cur; __syncthreads();
    const float* W = hw + (size_t)i*CCH*CCH;
    float acc = hb[i*CCH + tid];
    for (int c = 0; c < CCH; ++c) acc += xa[c] * W[c*CCH + tid];
    cur = acc > 0.f ? acc : 0.2f*acc;
    __syncthreads();
  }
  return cur;
}

// K8: lat + all three MLPs + softmaxes + amps. One 128-thread block per event.
__global__ __launch_bounds__(128) void k_mlp(
    const float* __restrict__ h, const float* __restrict__ scal,
    const float* __restrict__ vals, const int* __restrict__ idxs,
    const float* __restrict__ a_hw, const float* __restrict__ a_hb,
    const float* __restrict__ a_ow, const float* __restrict__ a_ob,
    const float* __restrict__ t_hw, const float* __restrict__ t_hb,
    const float* __restrict__ t_ow, const float* __restrict__ t_ob,
    const float* __restrict__ m_hw, const float* __restrict__ m_hb,
    const float* __restrict__ m_ow, const float* __restrict__ m_ob,
    float* __restrict__ p_atoms, float* __restrict__ p_trans, float* __restrict__ amps) {
  const int row = blockIdx.x;
  const int b = row >> 5;
  const int tid = threadIdx.x;
  __shared__ float xa[CCH];
  __shared__ float red[CCH];
  const int t = idxs[row];
  const float latv = h[((size_t)b*TSAMP + t)*CCH + tid] * scal[b] * vals[row];

  {
    const float cur = mlp_hidden3(latv, a_hw, a_hb, xa);
    xa[tid] = cur; __syncthreads();
    float l0 = a_ob[tid], l1 = a_ob[tid+128], l2 = a_ob[tid+256], l3 = a_ob[tid+384];
    for (int c = 0; c < CCH; ++c) {
      const float xv = xa[c];
      const float* W = a_ow + (size_t)c*NATOMS + tid;
      l0 += xv*W[0]; l1 += xv*W[128]; l2 += xv*W[256]; l3 += xv*W[384];
    }
    const float mx = blk_max128(fmaxf(fmaxf(l0,l1), fmaxf(l2,l3)), red);
    const float e0 = expf(l0-mx), e1 = expf(l1-mx), e2 = expf(l2-mx), e3 = expf(l3-mx);
    const float inv = 1.f / blk_sum128(e0+e1+e2+e3, red);
    float* pa = p_atoms + (size_t)row*NATOMS;
    pa[tid] = e0*inv; pa[tid+128] = e1*inv; pa[tid+256] = e2*inv; pa[tid+384] = e3*inv;
  }
  {
    const float cur = mlp_hidden3(latv, t_hw, t_hb, xa);
    xa[tid] = cur; __syncthreads();
    float lg = -3.4e38f;
    if (tid < NTRANS) {
      float acc = t_ob[tid];
      for (int c = 0; c < CCH; ++c) acc += xa[c]*t_ow[c*NTRANS + tid];
      lg = acc;
    }
    const float mt = blk_max128(lg, red);
    const float et = (tid < NTRANS) ? expf(lg - mt) : 0.f;
    const float st = blk_sum128(et, red);
    if (tid < NTRANS) p_trans[(size_t)row*NTRANS + tid] = et/st;
  }
  {
    const float cur = mlp_hidden3(latv, m_hw, m_hb, xa);
    const float s = blk_sum128(cur * m_ow[tid], red);
    if (tid == 0) { const float v = s + m_ob[0]; amps[row] = v*v; }
  }
}

// K9: atoms_vec[row,:] = p_atoms[row] @ atoms_dict (512x512)
__global__ __launch_bounds__(256) void k_atoms_mm(const float* __restrict__ p_atoms,
                                                  const float* __restrict__ dict,
                                                  float* __restrict__ av) {
  const int row = blockIdx.x;
  __shared__ float p[NATOMS];
  for (int i = threadIdx.x; i < NATOMS; i += 256) p[i] = p_atoms[(size_t)row*NATOMS + i];
  __syncthreads();
  const int s0 = threadIdx.x*2;
  float a0=0, a1=0;
  for (int a = 0; a < NATOMS; ++a) {
    const float pa = p[a];
    const float2 dv = *(const float2*)(dict + (size_t)a*ASIZE + s0);
    a0 += pa*dv.x; a1 += pa*dv.y;
  }
  av[(size_t)row*ASIZE + s0] = a0; av[(size_t)row*ASIZE + s0 + 1] = a1;
}

// K10: transfers[row,:] = p_trans[row] @ transfer_dict (64x8192)
__global__ __launch_bounds__(256) void k_trans_mm(const float* __restrict__ p_trans,
                                                   const float* __restrict__ td,
                                                   float* __restrict__ trans) {
  const int row = blockIdx.y;
  const int t = blockIdx.x*2048 + threadIdx.x*8;
  __shared__ float p[NTRANS];
  if (threadIdx.x < NTRANS) p[threadIdx.x] = p_trans[(size_t)row*NTRANS + threadIdx.x];
  __syncthreads();
  float a0=0,a1=0,a2=0,a3=0,a4=0,a5=0,a6=0,a7=0;
  for (int j = 0; j < NTRANS; ++j) {
    const float pj = p[j];
    const float4 v0 = *(const float4*)(td + (size_t)j*TSIZE + t);
    const float4 v1 = *(const float4*)(td + (size_t)j*TSIZE + t + 4);
    a0 += pj*v0.x; a1 += pj*v0.y; a2 += pj*v0.z; a3 += pj*v0.w;
    a4 += pj*v1.x; a5 += pj*v1.y; a6 += pj*v1.z; a7 += pj*v1.w;
  }
  float* o = trans + (size_t)row*TSIZE + t;
  o[0]=a0; o[1]=a1; o[2]=a2; o[3]=a3; o[4]=a4; o[5]=a5; o[6]=a6; o[7]=a7;
}

// K11: ev conv; rolling window with EPAD skew
__global__ __launch_bounds__(256) void k_ev(const float* __restrict__ trans,
                                            const float* __restrict__ av,
                                            const float* __restrict__ amps,
                                            float* __restrict__ ev) {
  const int row = blockIdx.y;
  const int t0 = blockIdx.x * 1024;
  __shared__ float al[512];
  __shared__ float tw[1584];
  for (int i = threadIdx.x; i < 512; i += 256) al[i] = av[(size_t)row*ASIZE + i];
  for (int i = threadIdx.x; i < 1536; i += 256) {
    const int g = t0 - 512 + i;
    tw[EPAD(i)] = (g >= 0) ? trans[(size_t)row*TSIZE + g] : 0.f;
  }
  __syncthreads();
  const int base = threadIdx.x*4 + 512;
  float a0=0,a1=0,a2=0,a3=0;
  float w0=tw[EPAD(base)], w1=tw[EPAD(base+1)], w2=tw[EPAD(base+2)], w3=tw[EPAD(base+3)];
#pragma unroll 8
  for (int k = 0; k < 512; ++k) {
    const float ak = al[k];
    a0 += ak*w0; a1 += ak*w1; a2 += ak*w2; a3 += ak*w3;
    w3 = w2; w2 = w1; w1 = w0;
    const int p = base - k - 1;
    w0 = tw[EPAD(p)];
  }
  const int n = t0 + threadIdx.x*4;
  const float amp = amps[row];
  float* e = ev + (size_t)row*TSIZE + n;
  e[0] = (a0 + (n+0 < 512 ? al[n+0] : 0.f)) * amp;
  e[1] = (a1 + (n+1 < 512 ? al[n+1] : 0.f)) * amp;
  e[2] = (a2 + (n+2 < 512 ? al[n+2] : 0.f)) * amp;
  e[3] = (a3 + (n+3 < 512 ? al[n+3] : 0.f)) * amp;
}

// K12: overlap-add gather, atomics-free; 256 blocks x 128 threads (full GPU).
__global__ __launch_bounds__(128) void k_dry(const float* __restrict__ ev,
                                             const int* __restrict__ idxs,
                                             float* __restrict__ dry,
                                             _Float16* __restrict__ drev) {
  __shared__ int sidx[NROWS];
  if (threadIdx.x < 128) {
    sidx[threadIdx.x] = idxs[threadIdx.x];
    sidx[threadIdx.x + 128] = idxs[threadIdx.x + 128];
  }
  __syncthreads();
  const int p = blockIdx.x*128 + threadIdx.x;
  float a = 0.f;
  for (int r = 0; r < NROWS; ++r) {
    const int off = p - sidx[r];
    if ((unsigned)off < TSIZE) a += ev[(size_t)r*TSIZE + off];
  }
  dry[p] = a;
  drev[TSAMP - 1 - p] = (_Float16)(a * DRY_SCALE);
}

// K14: impulse[b,t] -> f16 hi only, ×2^6
__global__ __launch_bounds__(256) void k_impulse(const float* __restrict__ roomp,
                                                 const float* __restrict__ rooms,
                                                 _Float16* __restrict__ ihi) {
  const int b = blockIdx.y;
  const int t = blockIdx.x*1024 + threadIdx.x*4;
  float a0=0,a1=0,a2=0,a3=0;
  for (int r = 0; r < 8; ++r) {
    const float pr = roomp[b*8 + r];
    const float4 v = *(const float4*)(rooms + (size_t)r*TSAMP + t);
    a0 += pr*v.x; a1 += pr*v.y; a2 += pr*v.z; a3 += pr*v.w;
  }
  _Float16* oh = ihi + (size_t)b*TSAMP + t;
  oh[0] = (_Float16)(a0*IMP_SCALE); oh[1] = (_Float16)(a1*IMP_SCALE);
  oh[2] = (_Float16)(a2*IMP_SCALE); oh[3] = (_Float16)(a3*IMP_SCALE);
}

// K15: reverb conv via f16 MFMA (hi-only), N=512/block, k-slab 4096.
__global__ __launch_bounds__(256) void k_wet_mfma(
    const _Float16* __restrict__ drev, const _Float16* __restrict__ ihi,
    float* __restrict__ wet) {
  const int t0 = blockIdx.x * 512;
  const int k0 = blockIdx.y * 4096;
  if (k0 > t0 + 511) return;
  __shared__ _Float16 rhi[8*1048];
  const int tid = threadIdx.x;
  const int wv = tid >> 6;
  const int lane = tid & 63;
  const int n16 = lane & 15;
  const int quad = lane >> 4;
  const int m = n16;

  f32x4 acc[8];
#pragma unroll
  for (int j = 0; j < 8; ++j) acc[j] = (f32x4){0.f,0.f,0.f,0.f};

  const int kend = (k0 + 4096 < t0 + 512) ? k0 + 4096 : t0 + 512;
  const int ph = 7 - (n16 & 7);
  for (int kc0 = k0; kc0 < kend; kc0 += 512) {
    const int RB = TSAMP - 1 - (t0 + 511 - kc0);
    for (int flat = tid; flat < 8*1016; flat += 256) {
      const int p = flat / 1016;
      const int q = flat - p*1016;
      rhi[p*1048 + q] = drev[RB + p + q];
    }
    __syncthreads();

#pragma unroll 4
    for (int kc = 0; kc < 16; ++kc) {
      const int kb = kc*32;
      const int jg = kc0 + kb + quad*8;
      f16x8 ah;
      if (m < NBATCH) ah = *(const f16x8*)(ihi + (size_t)m*TSAMP + jg);
      else ah = (f16x8){0,0,0,0,0,0,0,0};
#pragma unroll
      for (int ts = 0; ts < 8; ++ts) {
        const int nn = wv*128 + ts*16 + n16;
        const int a = ph*1048 + kb + quad*8 + 504 - (nn & ~7);
        const f16x8 bh = *(const f16x8*)(rhi + a);
        acc[ts] = __builtin_amdgcn_mfma_f32_16x16x32_f16(ah, bh, acc[ts], 0, 0, 0);
      }
    }
    __syncthreads();
  }

#pragma unroll
  for (int ts = 0; ts < 8; ++ts) {
    const int t = t0 + wv*128 + ts*16 + n16;
#pragma unroll
    for (int r = 0; r < 4; ++r) {
      const int b = quad*4 + r;
      if (b < NBATCH)
        atomicAdd(wet + (size_t)b*TSAMP + t, acc[ts][r] * WET_DESCALE);
    }
  }
}

// K16: out = dry*(1-mix) + wet*mix
__global__ __launch_bounds__(256) void k_out(const float* __restrict__ dry,
                                             const float* __restrict__ wet,
                                             const float* __restrict__ mix,
                                             float* __restrict__ out) {
  const int b = blockIdx.y;
  const int t = blockIdx.x*1024 + threadIdx.x*4;
  const float m = mix[b];
  const float4 d = *(const float4*)(dry + t);
  const float4 w = *(const float4*)(wet + (size_t)b*TSAMP + t);
  float* o = out + (size_t)b*TSAMP + t;
  o[0] = d.x*(1.f-m) + w.x*m;
  o[1] = d.y*(1.f-m) + w.y*m;
  o[2] = d.z*(1.f-m) + w.z*m;
  o[3] = d.w*(1.f-m) + w.w*m;
}

// ------------------------------------------------------------------
extern "C" void kernel_launch(void* const* d_in, const int* in_sizes, int n_in,
                              void* d_out, int out_size, void* d_ws, size_t ws_size,
                              hipStream_t stream) {
  (void)in_sizes; (void)n_in; (void)out_size; (void)ws_size;
  const float* x      = (const float*)d_in[0];
  const float* bank   = (const float*)d_in[1];
  const float* w_net  = (const float*)d_in[2];
  const float* b_net  = (const float*)d_in[3];
  const float* attn_w = (const float*)d_in[4];
  const float* attn_b = (const float*)d_in[5];
  const float* a_hw = (const float*)d_in[6];
  const float* a_hb = (const float*)d_in[7];
  const float* a_ow = (const float*)d_in[8];
  const float* a_ob = (const float*)d_in[9];
  const float* t_hw = (const float*)d_in[10];
  const float* t_hb = (const float*)d_in[11];
  const float* t_ow = (const float*)d_in[12];
  const float* t_ob = (const float*)d_in[13];
  const float* m_hw = (const float*)d_in[14];
  const float* m_hb = (const float*)d_in[15];
  const float* m_ow = (const float*)d_in[16];
  const float* m_ob = (const float*)d_in[17];
  const float* atoms_dict    = (const float*)d_in[18];
  const float* transfer_dict = (const float*)d_in[19];
  const float* rooms  = (const float*)d_in[20];
  const float* room_w = (const float*)d_in[21];
  const float* room_b = (const float*)d_in[22];
  const float* mix_w  = (const float*)d_in[23];
  const float* mix_b  = (const float*)d_in[24];
  float* out = (float*)d_out;

  // ---- workspace (~204 MB): H | t1 | t2 | weights | stats (R11-proven)
  float* ws = (float*)d_ws;
  const size_t S = (size_t)CCH * TSAMP;
  float* H  = ws;                               // [B][T][C]
  float* t1 = ws + (size_t)33554432;
  float* t2 = ws + (size_t)41943040;
  _Float16* whi = (_Float16*)(ws + (size_t)50331648);
  _Float16* wlo = whi + 245760;
  _Float16* bhi = wlo + 245760;
  _Float16* blo = bhi + 65536;
  double* sums   = (double*)(ws + (size_t)50642944);   // 16 doubles
  float* attnraw = ws + (size_t)50642976;              // 8*32768
  float* pm      = attnraw + (size_t)NBATCH*TSAMP;     // 8*256*128

  size_t off = 33554432;                       // scratch base (aliases t1)
  float* scal  = ws + off; off += 8;
  float* vals  = ws + off; off += NROWS;
  int*   idxs  = (int*)(ws + off); off += NROWS;
  float* p_atoms = ws + off; off += (size_t)NROWS*NATOMS;
  float* p_trans = ws + off; off += (size_t)NROWS*NTRANS;
  float* amps  = ws + off; off += NROWS;
  float* av    = ws + off; off += (size_t)NROWS*ASIZE;
  float* trans = ws + off; off += (size_t)NROWS*TSIZE;
  float* ev    = ws + off; off += (size_t)NROWS*TSIZE;
  float* dry   = ws + off; off += TSAMP;
  float* roomp = ws + off; off += 64;
  float* mix   = ws + off; off += 8;
  float* wet   = ws + off; off += (size_t)NBATCH*TSAMP;
  float* cand_v = ws + off; off += 4096;
  int*   cand_i = (int*)(ws + off); off += 4096;
  _Float16* imphi = (_Float16*)(ws + off); off += (size_t)NBATCH*TSAMP/2;
  _Float16* drev  = (_Float16*)(ws + off); off += (TSAMP + 1088)/2 + 4;
  // scratch ends ~38.6M floats < t2 start — disjoint.

  k_prep<<<1216, 256, 0, stream>>>(w_net, bank, whi, wlo, bhi, blo, sums);
  k_front_mfma<<<dim3(256, 8), 256, 0, stream>>>(x, bhi, blo, H);

  const int dil[5] = {1, 3, 9, 27, 1};
  for (int p = 0; p < 4; ++p) {            // 2 batches per dispatch
    float* Hp = H + (size_t)(2*p) * S;
    float* io[6] = {Hp, t1, t2, t1, t2, Hp};
    {                                      // layer 0 (d=1): 96-t, 3 blocks/CU
      const size_t smem = (size_t)98 * 544;
      k_dil96<<<dim3(342, 2), 256, smem, stream>>>(
          io[0], whi, wlo, b_net, io[1], 1);
    }
    for (int i = 1; i < 3; ++i) {          // d = 3, 9: 128-t tiles
      const int d = dil[i];
      const size_t smem = (size_t)(128 + 2*d) * 544;
      k_dil128<<<dim3(256, 2), 256, smem, stream>>>(
          io[i], whi + (size_t)i*49152, wlo + (size_t)i*49152, b_net + i*CCH,
          io[i+1], d);
    }
    {                                      // d = 27: 80-t tiles
      const size_t smem = (size_t)134 * 544;
      k_dil80<<<dim3(410, 2), 256, smem, stream>>>(
          io[3], whi + (size_t)3*49152, wlo + (size_t)3*49152, b_net + 3*CCH,
          io[4]);
    }
    {                                      // last layer d=1: 128-t + stats
      const int d = dil[4];
      const size_t smem = (size_t)(128 + 2*d) * 544;
      k_dil_last<<<dim3(256, 2), 256, smem, stream>>>(
          io[4], whi + (size_t)4*49152, wlo + (size_t)4*49152, b_net + 4*CCH,
          io[5], d, attn_w, sums, attnraw, pm, 2*p);
    }
  }

  k_zero<<<1024, 256, 0, stream>>>(wet, drev);
  k_finish<<<8, 128, 0, stream>>>(sums, pm, room_w, room_b, mix_w, mix_b,
                                  scal, roomp, mix);
  k_topk1<<<dim3(16, 8), 256, 0, stream>>>(attnraw, scal, attn_b, cand_v, cand_i);
  k_topk2<<<8, 512, 0, stream>>>(cand_v, cand_i, vals, idxs);
  k_mlp<<<256, 128, 0, stream>>>(H, scal, vals, idxs,
                                 a_hw, a_hb, a_ow, a_ob,
                                 t_hw, t_hb, t_ow, t_ob,
                                 m_hw, m_hb, m_ow, m_ob,
                                 p_atoms, p_trans, amps);
  k_atoms_mm<<<256, 256, 0, stream>>>(p_atoms, atoms_dict, av);
  k_trans_mm<<<dim3(4, 256), 256, 0, stream>>>(p_trans, transfer_dict, trans);
  k_ev<<<dim3(8, 256), 256, 0, stream>>>(trans, av, amps, ev);
  k_dry<<<256, 128, 0, stream>>>(ev, idxs, dry, drev);
  k_impulse<<<dim3(32, 8), 256, 0, stream>>>(roomp, rooms, imphi);
  k_wet_mfma<<<dim3(64, 8), 256, 0, stream>>>(drev, imphi, wet);
  k_out<<<dim3(32, 8), 256, 0, stream>>>(dry, wet, mix, out);
}

// Round 14
// 1213.420 us; speedup vs baseline: 1.3326x; 1.0411x over previous
//
#include <hip/hip_runtime.h>
#include <math.h>

#define TSAMP 32768
#define CCH 128
#define NBATCH 8
#define NEV 32
#define NROWS 256   // NBATCH*NEV
#define NATOMS 512
#define ASIZE 512
#define NTRANS 64
#define TSIZE 8192

#define DRY_SCALE 16777216.0f               // 2^24
#define IMP_SCALE 64.0f                     // 2^6
#define WET_DESCALE 9.313225746154785e-10f  // 2^-30

// LDS skew for stride-4 lane patterns: 8-way conflict -> 2-way (free)
#define EPAD(i) ((i) + ((i) >> 5))

typedef _Float16 f16x8 __attribute__((ext_vector_type(8)));
typedef _Float16 f16x4 __attribute__((ext_vector_type(4)));
typedef float f32x4 __attribute__((ext_vector_type(4)));

// activations stored [B][T][C] (c contiguous).

// ------------------------------------------------------------------
// K-prep: split conv weights ([layer][k][o][ci]) + filter bank ([c][k]) to
// f16 hi/lo, and zero the f64 stat sums. One dispatch.
__global__ __launch_bounds__(256) void k_prep(const float* __restrict__ wn,
                                              const float* __restrict__ bank,
                                              _Float16* __restrict__ whi,
                                              _Float16* __restrict__ wlo,
                                              _Float16* __restrict__ bhi,
                                              _Float16* __restrict__ blo,
                                              double* __restrict__ sums) {
  const int i = blockIdx.x * 256 + threadIdx.x;
  if (i < 16) sums[i] = 0.0;
  if (i < 245760) {
    const int ci = i & 127;
    int r = i >> 7;
    const int o = r & 127;
    r >>= 7;
    const int k = r % 3;
    const int l = r / 3;
    const float w = wn[(((size_t)l*128 + o)*128 + ci)*3 + k];
    const _Float16 hi = (_Float16)w;
    whi[i] = hi;
    wlo[i] = (_Float16)(w - (float)hi);
  } else if (i < 311296) {
    const int j = i - 245760;
    const float w = bank[j];
    const _Float16 hi = (_Float16)w;
    bhi[j] = hi;
    blo[j] = (_Float16)(w - (float)hi);
  }
}

// K0: zero wet accumulator + drev zero-pad tail
__global__ __launch_bounds__(256) void k_zero(float* __restrict__ wet,
                                              _Float16* __restrict__ drev) {
  int i = blockIdx.x * 256 + threadIdx.x;
  if (i < NBATCH * TSAMP) wet[i] = 0.f;
  if (i < 1088) drev[TSAMP + i] = (_Float16)0.f;
}

// ------------------------------------------------------------------
// K1: front filter bank via split-f16 MFMA, 128-t blocks (8 ts tiles/wave).
__global__ __launch_bounds__(256) void k_front_mfma(
    const float* __restrict__ x, const _Float16* __restrict__ bhi,
    const _Float16* __restrict__ blo, float* __restrict__ h) {
  __shared__ _Float16 shi[8*664];
  __shared__ _Float16 slo[8*664];
  const int t0 = blockIdx.x * 128;
  const int b  = blockIdx.y;
  const float* xb = x + (size_t)b*TSAMP;
  const int tid = threadIdx.x;

  for (int flat = tid; flat < 8*632; flat += 256) {
    const int p = flat / 632;
    const int q = flat - p*632;
    const int g = t0 - 256 + q + p;
    const float v = (g >= 0 && g < TSAMP) ? xb[g] : 0.f;
    const _Float16 hi = (_Float16)v;
    shi[p*664 + q] = hi;
    slo[p*664 + q] = (_Float16)(v - (float)hi);
  }
  __syncthreads();

  const int wv = tid >> 6;
  const int lane = tid & 63;
  const int n = lane & 15;
  const int quad = lane >> 4;
  const int c0 = wv * 32;
  const int ph = n & 7;
  const int nb = n & 8;

  f32x4 acc[2][8];
#pragma unroll
  for (int i = 0; i < 2; ++i)
#pragma unroll
    for (int j = 0; j < 8; ++j) acc[i][j] = (f32x4){0.f,0.f,0.f,0.f};

  for (int kc = 0; kc < 16; ++kc) {
    const int kb = kc*32 + quad*8;
    f16x8 ahi[2], alo[2];
#pragma unroll
    for (int os = 0; os < 2; ++os) {
      const size_t ao = (size_t)(c0 + os*16 + n)*512 + kb;
      ahi[os] = *(const f16x8*)(bhi + ao);
      alo[os] = *(const f16x8*)(blo + ao);
    }
#pragma unroll
    for (int tg = 0; tg < 2; ++tg) {
      f16x8 xh[4], xl[4];
#pragma unroll
      for (int u = 0; u < 4; ++u) {
        const int a = ph*664 + (tg*4 + u)*16 + nb + kb;
        xh[u] = *(const f16x8*)(shi + a);
        xl[u] = *(const f16x8*)(slo + a);
      }
#pragma unroll
      for (int os = 0; os < 2; ++os)
#pragma unroll
        for (int u = 0; u < 4; ++u) {
          f32x4 a4 = acc[os][tg*4 + u];
          a4 = __builtin_amdgcn_mfma_f32_16x16x32_f16(ahi[os], xh[u], a4, 0, 0, 0);
          a4 = __builtin_amdgcn_mfma_f32_16x16x32_f16(alo[os], xh[u], a4, 0, 0, 0);
          a4 = __builtin_amdgcn_mfma_f32_16x16x32_f16(ahi[os], xl[u], a4, 0, 0, 0);
          acc[os][tg*4 + u] = a4;
        }
    }
  }

  float* hb = h + (size_t)b*TSAMP*CCH;
#pragma unroll
  for (int os = 0; os < 2; ++os) {
    const int cb = c0 + os*16 + quad*4;
#pragma unroll
    for (int ts = 0; ts < 8; ++ts) {
      const int t = t0 + ts*16 + n;
      *(f32x4*)(hb + (size_t)t*CCH + cb) = acc[os][ts];
    }
  }
}

// ------------------------------------------------------------------
// K2a: 80-t dilated conv layer for d=27 (LDS 72.9 KB -> 2 blocks/CU).
__global__ __launch_bounds__(256) void k_dil80(
    const float* __restrict__ hin0, const _Float16* __restrict__ whi,
    const _Float16* __restrict__ wlo, const float* __restrict__ bias,
    float* __restrict__ hout0) {
  const int d = 27;
  extern __shared__ _Float16 sh[];
  const int twin = 80 + 2*d;              // 134
  _Float16* shi = sh;
  _Float16* slo = sh + twin*136;
  const int t0 = blockIdx.x * 80;
  const size_t bs = (size_t)blockIdx.y * CCH * TSAMP;
  const float* __restrict__ hin = hin0 + bs;
  float* __restrict__ hout = hout0 + bs;
  const int tid = threadIdx.x;

  for (int flat = tid; flat < twin*32; flat += 256) {
    const int tw = flat >> 5;
    const int c4 = (flat & 31) << 2;
    const int g = t0 - d + tw;
    float4 v = {0.f, 0.f, 0.f, 0.f};
    if (g >= 0 && g < TSAMP) v = *(const float4*)(hin + (size_t)g*CCH + c4);
    f16x4 hv, lv;
    hv[0] = (_Float16)v.x; hv[1] = (_Float16)v.y;
    hv[2] = (_Float16)v.z; hv[3] = (_Float16)v.w;
    lv[0] = (_Float16)(v.x - (float)hv[0]); lv[1] = (_Float16)(v.y - (float)hv[1]);
    lv[2] = (_Float16)(v.z - (float)hv[2]); lv[3] = (_Float16)(v.w - (float)hv[3]);
    *(f16x4*)(shi + tw*136 + c4) = hv;
    *(f16x4*)(slo + tw*136 + c4) = lv;
  }
  __syncthreads();

  const int wv = tid >> 6;
  const int lane = tid & 63;
  const int n = lane & 15;
  const int quad = lane >> 4;
  const int o0 = wv * 32;

  f32x4 acc[2][5];
#pragma unroll
  for (int i = 0; i < 2; ++i)
#pragma unroll
    for (int j = 0; j < 5; ++j) acc[i][j] = (f32x4){0.f,0.f,0.f,0.f};

  for (int k = 0; k < 3; ++k) {
    for (int kc = 0; kc < 4; ++kc) {
      const int cib = kc*32 + quad*8;
      f16x8 ahi[2], alo[2];
#pragma unroll
      for (int os = 0; os < 2; ++os) {
        const size_t wo = ((size_t)k*128 + (o0 + os*16 + n))*128 + cib;
        ahi[os] = *(const f16x8*)(whi + wo);
        alo[os] = *(const f16x8*)(wlo + wo);
      }
      f16x8 bh[5], bl[5];
#pragma unroll
      for (int ts = 0; ts < 5; ++ts) {
        const int a = (ts*16 + n + k*d)*136 + cib;
        bh[ts] = *(const f16x8*)(shi + a);
        bl[ts] = *(const f16x8*)(slo + a);
      }
#pragma unroll
      for (int os = 0; os < 2; ++os)
#pragma unroll
        for (int ts = 0; ts < 5; ++ts) {
          acc[os][ts] = __builtin_amdgcn_mfma_f32_16x16x32_f16(ahi[os], bh[ts], acc[os][ts], 0, 0, 0);
          acc[os][ts] = __builtin_amdgcn_mfma_f32_16x16x32_f16(alo[os], bh[ts], acc[os][ts], 0, 0, 0);
          acc[os][ts] = __builtin_amdgcn_mfma_f32_16x16x32_f16(ahi[os], bl[ts], acc[os][ts], 0, 0, 0);
        }
    }
  }

#pragma unroll
  for (int os = 0; os < 2; ++os) {
    const int ob = o0 + os*16 + quad*4;
    const f32x4 bs4 = *(const f32x4*)(bias + ob);
#pragma unroll
    for (int ts = 0; ts < 5; ++ts) {
      const int t = t0 + ts*16 + n;
      if (t < TSAMP) {
        const int tw = ts*16 + n + d;
        const f16x4 phv = *(const f16x4*)(shi + tw*136 + ob);
        const f16x4 plv = *(const f16x4*)(slo + tw*136 + ob);
        f32x4 res;
#pragma unroll
        for (int r = 0; r < 4; ++r) {
          float v = acc[os][ts][r] + bs4[r];
          v = v > 0.f ? v : 0.2f*v;
          res[r] = (float)phv[r] + (float)plv[r] + v;
        }
        *(f32x4*)(hout + (size_t)t*CCH + ob) = res;
      }
    }
  }
}

// ------------------------------------------------------------------
// K2b: 128-t dilated conv layer (d<=9): 576 MFMA/wave, 8 acc chains.
__global__ __launch_bounds__(256) void k_dil128(
    const float* __restrict__ hin0, const _Float16* __restrict__ whi,
    const _Float16* __restrict__ wlo, const float* __restrict__ bias,
    float* __restrict__ hout0, const int d) {
  extern __shared__ _Float16 sh[];
  const int twin = 128 + 2*d;
  _Float16* shi = sh;
  _Float16* slo = sh + twin*136;
  const int t0 = blockIdx.x * 128;
  const size_t bs = (size_t)blockIdx.y * CCH * TSAMP;
  const float* __restrict__ hin = hin0 + bs;
  float* __restrict__ hout = hout0 + bs;
  const int tid = threadIdx.x;

  for (int flat = tid; flat < twin*32; flat += 256) {
    const int tw = flat >> 5;
    const int c4 = (flat & 31) << 2;
    const int g = t0 - d + tw;
    float4 v = {0.f, 0.f, 0.f, 0.f};
    if (g >= 0 && g < TSAMP) v = *(const float4*)(hin + (size_t)g*CCH + c4);
    f16x4 hv, lv;
    hv[0] = (_Float16)v.x; hv[1] = (_Float16)v.y;
    hv[2] = (_Float16)v.z; hv[3] = (_Float16)v.w;
    lv[0] = (_Float16)(v.x - (float)hv[0]); lv[1] = (_Float16)(v.y - (float)hv[1]);
    lv[2] = (_Float16)(v.z - (float)hv[2]); lv[3] = (_Float16)(v.w - (float)hv[3]);
    *(f16x4*)(shi + tw*136 + c4) = hv;
    *(f16x4*)(slo + tw*136 + c4) = lv;
  }
  __syncthreads();

  const int wv = tid >> 6;
  const int lane = tid & 63;
  const int n = lane & 15;
  const int quad = lane >> 4;
  const int o0 = wv * 32;

  f32x4 acc[2][8];
#pragma unroll
  for (int i = 0; i < 2; ++i)
#pragma unroll
    for (int j = 0; j < 8; ++j) acc[i][j] = (f32x4){0.f,0.f,0.f,0.f};

  for (int k = 0; k < 3; ++k) {
    for (int kc = 0; kc < 4; ++kc) {
      const int cib = kc*32 + quad*8;
      f16x8 ahi[2], alo[2];
#pragma unroll
      for (int os = 0; os < 2; ++os) {
        const size_t wo = ((size_t)k*128 + (o0 + os*16 + n))*128 + cib;
        ahi[os] = *(const f16x8*)(whi + wo);
        alo[os] = *(const f16x8*)(wlo + wo);
      }
#pragma unroll
      for (int tg = 0; tg < 2; ++tg) {
        f16x8 bh[4], bl[4];
#pragma unroll
        for (int u = 0; u < 4; ++u) {
          const int a = ((tg*4 + u)*16 + n + k*d)*136 + cib;
          bh[u] = *(const f16x8*)(shi + a);
          bl[u] = *(const f16x8*)(slo + a);
        }
#pragma unroll
        for (int os = 0; os < 2; ++os)
#pragma unroll
          for (int u = 0; u < 4; ++u) {
            f32x4 a4 = acc[os][tg*4 + u];
            a4 = __builtin_amdgcn_mfma_f32_16x16x32_f16(ahi[os], bh[u], a4, 0, 0, 0);
            a4 = __builtin_amdgcn_mfma_f32_16x16x32_f16(alo[os], bh[u], a4, 0, 0, 0);
            a4 = __builtin_amdgcn_mfma_f32_16x16x32_f16(ahi[os], bl[u], a4, 0, 0, 0);
            acc[os][tg*4 + u] = a4;
          }
      }
    }
  }

#pragma unroll
  for (int os = 0; os < 2; ++os) {
    const int ob = o0 + os*16 + quad*4;
    const f32x4 bs4 = *(const f32x4*)(bias + ob);
#pragma unroll
    for (int ts = 0; ts < 8; ++ts) {
      const int t = t0 + ts*16 + n;
      const int tw = ts*16 + n + d;
      const f16x4 phv = *(const f16x4*)(shi + tw*136 + ob);
      const f16x4 plv = *(const f16x4*)(slo + tw*136 + ob);
      f32x4 res;
#pragma unroll
      for (int r = 0; r < 4; ++r) {
        float v = acc[os][ts][r] + bs4[r];
        v = v > 0.f ? v : 0.2f*v;
        res[r] = (float)phv[r] + (float)plv[r] + v;
      }
      *(f32x4*)(hout + (size_t)t*CCH + ob) = res;
    }
  }
}

// ------------------------------------------------------------------
// K2c: LAST layer (d=1), 128-t, with fused stats/attn/context epilogue.
__global__ __launch_bounds__(256) void k_dil_last(
    const float* __restrict__ hin0, const _Float16* __restrict__ whi,
    const _Float16* __restrict__ wlo, const float* __restrict__ bias,
    float* __restrict__ hout0, const int d,
    const float* __restrict__ aw, double* __restrict__ sums,
    float* __restrict__ attnraw, float* __restrict__ pm, const int bb0) {
  extern __shared__ _Float16 sh[];
  const int twin = 128 + 2*d;
  _Float16* shi = sh;
  _Float16* slo = sh + twin*136;
  __shared__ float attl[4*128];
  __shared__ double sred[8];
  const int t0 = blockIdx.x * 128;
  const int b = bb0 + blockIdx.y;
  const size_t bs = (size_t)blockIdx.y * CCH * TSAMP;
  const float* __restrict__ hin = hin0 + bs;
  float* __restrict__ hout = hout0 + bs;
  const int tid = threadIdx.x;

  for (int flat = tid; flat < twin*32; flat += 256) {
    const int tw = flat >> 5;
    const int c4 = (flat & 31) << 2;
    const int g = t0 - d + tw;
    float4 v = {0.f, 0.f, 0.f, 0.f};
    if (g >= 0 && g < TSAMP) v = *(const float4*)(hin + (size_t)g*CCH + c4);
    f16x4 hv, lv;
    hv[0] = (_Float16)v.x; hv[1] = (_Float16)v.y;
    hv[2] = (_Float16)v.z; hv[3] = (_Float16)v.w;
    lv[0] = (_Float16)(v.x - (float)hv[0]); lv[1] = (_Float16)(v.y - (float)hv[1]);
    lv[2] = (_Float16)(v.z - (float)hv[2]); lv[3] = (_Float16)(v.w - (float)hv[3]);
    *(f16x4*)(shi + tw*136 + c4) = hv;
    *(f16x4*)(slo + tw*136 + c4) = lv;
  }
  __syncthreads();

  const int wv = tid >> 6;
  const int lane = tid & 63;
  const int n = lane & 15;
  const int quad = lane >> 4;
  const int o0 = wv * 32;

  f32x4 acc[2][8];
#pragma unroll
  for (int i = 0; i < 2; ++i)
#pragma unroll
    for (int j = 0; j < 8; ++j) acc[i][j] = (f32x4){0.f,0.f,0.f,0.f};

  for (int k = 0; k < 3; ++k) {
    for (int kc = 0; kc < 4; ++kc) {
      const int cib = kc*32 + quad*8;
      f16x8 ahi[2], alo[2];
#pragma unroll
      for (int os = 0; os < 2; ++os) {
        const size_t wo = ((size_t)k*128 + (o0 + os*16 + n))*128 + cib;
        ahi[os] = *(const f16x8*)(whi + wo);
        alo[os] = *(const f16x8*)(wlo + wo);
      }
#pragma unroll
      for (int tg = 0; tg < 2; ++tg) {
        f16x8 bh[4], bl[4];
#pragma unroll
        for (int u = 0; u < 4; ++u) {
          const int a = ((tg*4 + u)*16 + n + k*d)*136 + cib;
          bh[u] = *(const f16x8*)(shi + a);
          bl[u] = *(const f16x8*)(slo + a);
        }
#pragma unroll
        for (int os = 0; os < 2; ++os)
#pragma unroll
          for (int u = 0; u < 4; ++u) {
            f32x4 a4 = acc[os][tg*4 + u];
            a4 = __builtin_amdgcn_mfma_f32_16x16x32_f16(ahi[os], bh[u], a4, 0, 0, 0);
            a4 = __builtin_amdgcn_mfma_f32_16x16x32_f16(alo[os], bh[u], a4, 0, 0, 0);
            a4 = __builtin_amdgcn_mfma_f32_16x16x32_f16(ahi[os], bl[u], a4, 0, 0, 0);
            acc[os][tg*4 + u] = a4;
          }
      }
    }
  }

  const f32x4 awq0 = *(const f32x4*)(aw + o0 + quad*4);
  const f32x4 awq1 = *(const f32x4*)(aw + o0 + 16 + quad*4);
  double s = 0.0, s2 = 0.0;
  float pa[8] = {0.f,0.f,0.f,0.f,0.f,0.f,0.f,0.f};
  f32x4 cm[2];
  cm[0] = (f32x4){-3.4e38f, -3.4e38f, -3.4e38f, -3.4e38f};
  cm[1] = cm[0];

#pragma unroll
  for (int os = 0; os < 2; ++os) {
    const int ob = o0 + os*16 + quad*4;
    const f32x4 bs4 = *(const f32x4*)(bias + ob);
    const f32x4 awv = os ? awq1 : awq0;
#pragma unroll
    for (int ts = 0; ts < 8; ++ts) {
      const int t = t0 + ts*16 + n;
      const int tw = ts*16 + n + d;
      const f16x4 phv = *(const f16x4*)(shi + tw*136 + ob);
      const f16x4 plv = *(const f16x4*)(slo + tw*136 + ob);
      f32x4 res;
      float dotp = 0.f;
#pragma unroll
      for (int r = 0; r < 4; ++r) {
        float v = acc[os][ts][r] + bs4[r];
        v = v > 0.f ? v : 0.2f*v;
        const float hv = (float)phv[r] + (float)plv[r] + v;
        res[r] = hv;
        s += (double)hv; s2 += (double)hv*(double)hv;
        dotp += hv * awv[r];
        cm[os][r] = fmaxf(cm[os][r], hv);
      }
      pa[ts] += dotp;
      *(f32x4*)(hout + (size_t)t*CCH + ob) = res;
    }
  }

#pragma unroll
  for (int ts = 0; ts < 8; ++ts) {
    pa[ts] += __shfl_xor(pa[ts], 16);
    pa[ts] += __shfl_xor(pa[ts], 32);
  }
  if (quad == 0) {
#pragma unroll
    for (int ts = 0; ts < 8; ++ts) attl[wv*128 + ts*16 + n] = pa[ts];
  }
#pragma unroll
  for (int mk = 1; mk <= 8; mk <<= 1)
#pragma unroll
    for (int os = 0; os < 2; ++os)
#pragma unroll
      for (int r = 0; r < 4; ++r)
        cm[os][r] = fmaxf(cm[os][r], __shfl_xor(cm[os][r], mk));
  if (n == 0) {
#pragma unroll
    for (int os = 0; os < 2; ++os)
      *(f32x4*)(pm + ((size_t)b*256 + blockIdx.x)*128 + o0 + os*16 + quad*4) = cm[os];
  }
  for (int sft = 32; sft; sft >>= 1) { s += __shfl_down(s, sft); s2 += __shfl_down(s2, sft); }
  if (lane == 0) { sred[wv*2] = s; sred[wv*2+1] = s2; }
  __syncthreads();
  if (tid < 128)
    attnraw[(size_t)b*TSAMP + t0 + tid] =
        attl[tid] + attl[128 + tid] + attl[256 + tid] + attl[384 + tid];
  if (tid == 0) {
    atomicAdd(&sums[b*2],   sred[0] + sred[2] + sred[4] + sred[6]);
    atomicAdd(&sums[b*2+1], sred[1] + sred[3] + sred[5] + sred[7]);
  }
}

// ------------------------------------------------------------------
// K-finish: per-batch scale + context (LDS only) + room softmax + mix.
__global__ __launch_bounds__(128) void k_finish(
    const double* __restrict__ sums, const float* __restrict__ pm,
    const float* __restrict__ room_w, const float* __restrict__ room_b,
    const float* __restrict__ mix_w, const float* __restrict__ mix_b,
    float* __restrict__ scal, float* __restrict__ roomp, float* __restrict__ mix) {
  const int b = blockIdx.x;
  const int tid = threadIdx.x;
  __shared__ float bs;
  __shared__ float ctx[128];
  if (tid == 0) {
    const double nn = (double)CCH * (double)TSAMP;
    const double mean = sums[b*2] / nn;
    double var = sums[b*2+1] / nn - mean*mean;
    if (var < 0.0) var = 0.0;
    const float sc = (float)(1.0 / (sqrt(var) + 1e-8));
    bs = sc;
    scal[b] = sc;
  }
  __syncthreads();
  float m = -3.4e38f;
  for (int s = 0; s < 256; ++s) m = fmaxf(m, pm[((size_t)b*256 + s)*128 + tid]);
  ctx[tid] = m * bs;
  __syncthreads();
  if (tid < 8) {
    const int r = tid;
    float acc = room_b[r];
    for (int c = 0; c < CCH; ++c) acc += ctx[c] * room_w[c*8 + r];
    float mm = acc;
    for (int s = 1; s < 8; s <<= 1) mm = fmaxf(mm, __shfl_xor(mm, s, 8));
    const float e = expf(acc - mm);
    float ss = e;
    for (int s = 1; s < 8; s <<= 1) ss += __shfl_xor(ss, s, 8);
    roomp[b*8 + r] = e / ss;
  } else if (tid == 8) {
    float a = mix_b[0];
    for (int c = 0; c < CCH; ++c) a += ctx[c] * mix_w[c];
    mix[b] = 1.f/(1.f+expf(-a));
  }
}

// ------------------------------------------------------------------
// K7a: per-2048-chunk top-32 (sigmoid fused into staging).
__global__ __launch_bounds__(256) void k_topk1(const float* __restrict__ raw,
                                               const float* __restrict__ scal,
                                               const float* __restrict__ ab,
                                               float* __restrict__ cv,
                                               int* __restrict__ cidx) {
  const int ch = blockIdx.x, b = blockIdx.y;
  const float sc = scal[b], bb_ = ab[0];
  const float* a = raw + (size_t)b*TSAMP + ch*2048;
  __shared__ float v[2048];
  __shared__ float rv[4]; __shared__ int ri[4];
  const int tid = threadIdx.x;
  for (int i = tid; i < 2048; i += 256)
    v[i] = 1.f/(1.f+expf(-(a[i]*sc + bb_)));
  __syncthreads();
  for (int e = 0; e < NEV; ++e) {
    float bv = -1e30f; int bi = 0;
    for (int i = tid; i < 2048; i += 256) {
      const float x = v[i];
      if (x > bv) { bv = x; bi = i; }
    }
    for (int s = 32; s; s >>= 1) {
      const float ov = __shfl_down(bv, s); const int oi = __shfl_down(bi, s);
      if (ov > bv || (ov == bv && oi < bi)) { bv = ov; bi = oi; }
    }
    if ((tid & 63) == 0) { rv[tid >> 6] = bv; ri[tid >> 6] = bi; }
    __syncthreads();
    if (tid == 0) {
      int bb = 0;
      for (int w2 = 1; w2 < 4; ++w2)
        if (rv[w2] > rv[bb] || (rv[w2] == rv[bb] && ri[w2] < ri[bb])) bb = w2;
      cv[(b*16 + ch)*NEV + e] = rv[bb];
      cidx[(b*16 + ch)*NEV + e] = ch*2048 + ri[bb];
      v[ri[bb]] = -1e30f;
    }
    __syncthreads();
  }
}

// K7b: final top-32 over 512 candidates
__global__ __launch_bounds__(512) void k_topk2(const float* __restrict__ cv,
                                               const int* __restrict__ ci_,
                                               float* __restrict__ vals,
                                               int* __restrict__ idxs) {
  const int b = blockIdx.x;
  const int tid = threadIdx.x;
  float my = cv[b*512 + tid];
  int   mi = ci_[b*512 + tid];
  __shared__ float rv[8]; __shared__ int ri[8];
  __shared__ float bvs; __shared__ int bis;
  for (int e = 0; e < NEV; ++e) {
    float bv = my; int bi = mi;
    for (int s = 32; s; s >>= 1) {
      const float ov = __shfl_down(bv, s); const int oi = __shfl_down(bi, s);
      if (ov > bv || (ov == bv && oi < bi)) { bv = ov; bi = oi; }
    }
    if ((tid & 63) == 0) { rv[tid >> 6] = bv; ri[tid >> 6] = bi; }
    __syncthreads();
    if (tid == 0) {
      int bb = 0;
      for (int w2 = 1; w2 < 8; ++w2)
        if (rv[w2] > rv[bb] || (rv[w2] == rv[bb] && ri[w2] < ri[bb])) bb = w2;
      vals[b*NEV + e] = rv[bb]; idxs[b*NEV + e] = ri[bb];
      bvs = rv[bb]; bis = ri[bb];
    }
    __syncthreads();
    if (mi == bis && my == bvs) my = -1e30f;
    __syncthreads();
  }
}

// ------------------------------------------------------------------
__device__ __forceinline__ float blk_max128(float v, float* red) {
  const int tid = threadIdx.x;
  red[tid] = v; __syncthreads();
  for (int s = 64; s > 0; s >>= 1) {
    if (tid < s) red[tid] = fmaxf(red[tid], red[tid + s]);
    __syncthreads();
  }
  const float r = red[0]; __syncthreads();
  return r;
}
__device__ __forceinline__ float blk_sum128(float v, float* red) {
  const int tid = threadIdx.x;
  red[tid] = v; __syncthreads();
  for (int s = 64; s > 0; s >>= 1) {
    if (tid < s) red[tid] += red[tid + s];
    __syncthreads();
  }
  const float r = red[0]; __syncthreads();
  return r;
}
__device__ __forceinline__ float mlp_hidden3(float latv, const float* __restrict__ hw,
                                             const float* __restrict__ hb, float* xa) {
  const int tid = threadIdx.x;
  float cur = latv;
  for (int i = 0; i < 3; ++i) {
    xa[tid] = cur; __syncthreads();
    const float* W = hw + (size_t)i*CCH*CCH;
    float acc = hb[i*CCH + tid];
    for (int c = 0; c < CCH; ++c) acc += xa[c] * W[c*CCH + tid];
    cur = acc > 0.f ? acc : 0.2f*acc;
    __syncthreads();
  }
  return cur;
}

// K8: lat + all three MLPs + softmaxes + amps. One 128-thread block per event.
__global__ __launch_bounds__(128) void k_mlp(
    const float* __restrict__ h, const float* __restrict__ scal,
    const float* __restrict__ vals, const int* __restrict__ idxs,
    const float* __restrict__ a_hw, const float* __restrict__ a_hb,
    const float* __restrict__ a_ow, const float* __restrict__ a_ob,
    const float* __restrict__ t_hw, const float* __restrict__ t_hb,
    const float* __restrict__ t_ow, const float* __restrict__ t_ob,
    const float* __restrict__ m_hw, const float* __restrict__ m_hb,
    const float* __restrict__ m_ow, const float* __restrict__ m_ob,
    float* __restrict__ p_atoms, float* __restrict__ p_trans, float* __restrict__ amps) {
  const int row = blockIdx.x;
  const int b = row >> 5;
  const int tid = threadIdx.x;
  __shared__ float xa[CCH];
  __shared__ float red[CCH];
  const int t = idxs[row];
  const float latv = h[((size_t)b*TSAMP + t)*CCH + tid] * scal[b] * vals[row];

  {
    const float cur = mlp_hidden3(latv, a_hw, a_hb, xa);
    xa[tid] = cur; __syncthreads();
    float l0 = a_ob[tid], l1 = a_ob[tid+128], l2 = a_ob[tid+256], l3 = a_ob[tid+384];
    for (int c = 0; c < CCH; ++c) {
      const float xv = xa[c];
      const float* W = a_ow + (size_t)c*NATOMS + tid;
      l0 += xv*W[0]; l1 += xv*W[128]; l2 += xv*W[256]; l3 += xv*W[384];
    }
    const float mx = blk_max128(fmaxf(fmaxf(l0,l1), fmaxf(l2,l3)), red);
    const float e0 = expf(l0-mx), e1 = expf(l1-mx), e2 = expf(l2-mx), e3 = expf(l3-mx);
    const float inv = 1.f / blk_sum128(e0+e1+e2+e3, red);
    float* pa = p_atoms + (size_t)row*NATOMS;
    pa[tid] = e0*inv; pa[tid+128] = e1*inv; pa[tid+256] = e2*inv; pa[tid+384] = e3*inv;
  }
  {
    const float cur = mlp_hidden3(latv, t_hw, t_hb, xa);
    xa[tid] = cur; __syncthreads();
    float lg = -3.4e38f;
    if (tid < NTRANS) {
      float acc = t_ob[tid];
      for (int c = 0; c < CCH; ++c) acc += xa[c]*t_ow[c*NTRANS + tid];
      lg = acc;
    }
    const float mt = blk_max128(lg, red);
    const float et = (tid < NTRANS) ? expf(lg - mt) : 0.f;
    const float st = blk_sum128(et, red);
    if (tid < NTRANS) p_trans[(size_t)row*NTRANS + tid] = et/st;
  }
  {
    const float cur = mlp_hidden3(latv, m_hw, m_hb, xa);
    const float s = blk_sum128(cur * m_ow[tid], red);
    if (tid == 0) { const float v = s + m_ob[0]; amps[row] = v*v; }
  }
}

// K9: atoms_vec[row,:] = p_atoms[row] @ atoms_dict (512x512)
__global__ __launch_bounds__(256) void k_atoms_mm(const float* __restrict__ p_atoms,
                                                  const float* __restrict__ dict,
                                                  float* __restrict__ av) {
  const int row = blockIdx.x;
  __shared__ float p[NATOMS];
  for (int i = threadIdx.x; i < NATOMS; i += 256) p[i] = p_atoms[(size_t)row*NATOMS + i];
  __syncthreads();
  const int s0 = threadIdx.x*2;
  float a0=0, a1=0;
  for (int a = 0; a < NATOMS; ++a) {
    const float pa = p[a];
    const float2 dv = *(const float2*)(dict + (size_t)a*ASIZE + s0);
    a0 += pa*dv.x; a1 += pa*dv.y;
  }
  av[(size_t)row*ASIZE + s0] = a0; av[(size_t)row*ASIZE + s0 + 1] = a1;
}

// K10: transfers[row,:] = p_trans[row] @ transfer_dict (64x8192)
__global__ __launch_bounds__(256) void k_trans_mm(const float* __restrict__ p_trans,
                                                   const float* __restrict__ td,
                                                   float* __restrict__ trans) {
  const int row = blockIdx.y;
  const int t = blockIdx.x*2048 + threadIdx.x*8;
  __shared__ float p[NTRANS];
  if (threadIdx.x < NTRANS) p[threadIdx.x] = p_trans[(size_t)row*NTRANS + threadIdx.x];
  __syncthreads();
  float a0=0,a1=0,a2=0,a3=0,a4=0,a5=0,a6=0,a7=0;
  for (int j = 0; j < NTRANS; ++j) {
    const float pj = p[j];
    const float4 v0 = *(const float4*)(td + (size_t)j*TSIZE + t);
    const float4 v1 = *(const float4*)(td + (size_t)j*TSIZE + t + 4);
    a0 += pj*v0.x; a1 += pj*v0.y; a2 += pj*v0.z; a3 += pj*v0.w;
    a4 += pj*v1.x; a5 += pj*v1.y; a6 += pj*v1.z; a7 += pj*v1.w;
  }
  float* o = trans + (size_t)row*TSIZE + t;
  o[0]=a0; o[1]=a1; o[2]=a2; o[3]=a3; o[4]=a4; o[5]=a5; o[6]=a6; o[7]=a7;
}

// K11: ev conv; rolling window with EPAD skew
__global__ __launch_bounds__(256) void k_ev(const float* __restrict__ trans,
                                            const float* __restrict__ av,
                                            const float* __restrict__ amps,
                                            float* __restrict__ ev) {
  const int row = blockIdx.y;
  const int t0 = blockIdx.x * 1024;
  __shared__ float al[512];
  __shared__ float tw[1584];
  for (int i = threadIdx.x; i < 512; i += 256) al[i] = av[(size_t)row*ASIZE + i];
  for (int i = threadIdx.x; i < 1536; i += 256) {
    const int g = t0 - 512 + i;
    tw[EPAD(i)] = (g >= 0) ? trans[(size_t)row*TSIZE + g] : 0.f;
  }
  __syncthreads();
  const int base = threadIdx.x*4 + 512;
  float a0=0,a1=0,a2=0,a3=0;
  float w0=tw[EPAD(base)], w1=tw[EPAD(base+1)], w2=tw[EPAD(base+2)], w3=tw[EPAD(base+3)];
#pragma unroll 8
  for (int k = 0; k < 512; ++k) {
    const float ak = al[k];
    a0 += ak*w0; a1 += ak*w1; a2 += ak*w2; a3 += ak*w3;
    w3 = w2; w2 = w1; w1 = w0;
    const int p = base - k - 1;
    w0 = tw[EPAD(p)];
  }
  const int n = t0 + threadIdx.x*4;
  const float amp = amps[row];
  float* e = ev + (size_t)row*TSIZE + n;
  e[0] = (a0 + (n+0 < 512 ? al[n+0] : 0.f)) * amp;
  e[1] = (a1 + (n+1 < 512 ? al[n+1] : 0.f)) * amp;
  e[2] = (a2 + (n+2 < 512 ? al[n+2] : 0.f)) * amp;
  e[3] = (a3 + (n+3 < 512 ? al[n+3] : 0.f)) * amp;
}

// K12: overlap-add gather, atomics-free: each block owns a 256-t strip over
// ALL 256 rows; writes dry and the reversed-scaled f16 drev directly.
__global__ __launch_bounds__(256) void k_dry(const float* __restrict__ ev,
                                             const int* __restrict__ idxs,
                                             float* __restrict__ dry,
                                             _Float16* __restrict__ drev) {
  __shared__ int sidx[NROWS];
  if (threadIdx.x < NROWS) sidx[threadIdx.x] = idxs[threadIdx.x];
  __syncthreads();
  const int p = blockIdx.x*256 + threadIdx.x;
  float a = 0.f;
  for (int r = 0; r < NROWS; ++r) {
    const int off = p - sidx[r];
    if ((unsigned)off < TSIZE) a += ev[(size_t)r*TSIZE + off];
  }
  dry[p] = a;
  drev[TSAMP - 1 - p] = (_Float16)(a * DRY_SCALE);
}

// K14: impulse[b,t] -> f16 hi only, ×2^6
__global__ __launch_bounds__(256) void k_impulse(const float* __restrict__ roomp,
                                                 const float* __restrict__ rooms,
                                                 _Float16* __restrict__ ihi) {
  const int b = blockIdx.y;
  const int t = blockIdx.x*1024 + threadIdx.x*4;
  float a0=0,a1=0,a2=0,a3=0;
  for (int r = 0; r < 8; ++r) {
    const float pr = roomp[b*8 + r];
    const float4 v = *(const float4*)(rooms + (size_t)r*TSAMP + t);
    a0 += pr*v.x; a1 += pr*v.y; a2 += pr*v.z; a3 += pr*v.w;
  }
  _Float16* oh = ihi + (size_t)b*TSAMP + t;
  oh[0] = (_Float16)(a0*IMP_SCALE); oh[1] = (_Float16)(a1*IMP_SCALE);
  oh[2] = (_Float16)(a2*IMP_SCALE); oh[3] = (_Float16)(a3*IMP_SCALE);
}

// K15: reverb conv via f16 MFMA (hi-only), N=512/block, k-slab 4096.
__global__ __launch_bounds__(256) void k_wet_mfma(
    const _Float16* __restrict__ drev, const _Float16* __restrict__ ihi,
    float* __restrict__ wet) {
  const int t0 = blockIdx.x * 512;
  const int k0 = blockIdx.y * 4096;
  if (k0 > t0 + 511) return;
  __shared__ _Float16 rhi[8*1048];
  const int tid = threadIdx.x;
  const int wv = tid >> 6;
  const int lane = tid & 63;
  const int n16 = lane & 15;
  const int quad = lane >> 4;
  const int m = n16;

  f32x4 acc[8];
#pragma unroll
  for (int j = 0; j < 8; ++j) acc[j] = (f32x4){0.f,0.f,0.f,0.f};

  const int kend = (k0 + 4096 < t0 + 512) ? k0 + 4096 : t0 + 512;
  const int ph = 7 - (n16 & 7);
  for (int kc0 = k0; kc0 < kend; kc0 += 512) {
    const int RB = TSAMP - 1 - (t0 + 511 - kc0);
    for (int flat = tid; flat < 8*1016; flat += 256) {
      const int p = flat / 1016;
      const int q = flat - p*1016;
      rhi[p*1048 + q] = drev[RB + p + q];
    }
    __syncthreads();

#pragma unroll 4
    for (int kc = 0; kc < 16; ++kc) {
      const int kb = kc*32;
      const int jg = kc0 + kb + quad*8;
      f16x8 ah;
      if (m < NBATCH) ah = *(const f16x8*)(ihi + (size_t)m*TSAMP + jg);
      else ah = (f16x8){0,0,0,0,0,0,0,0};
#pragma unroll
      for (int ts = 0; ts < 8; ++ts) {
        const int nn = wv*128 + ts*16 + n16;
        const int a = ph*1048 + kb + quad*8 + 504 - (nn & ~7);
        const f16x8 bh = *(const f16x8*)(rhi + a);
        acc[ts] = __builtin_amdgcn_mfma_f32_16x16x32_f16(ah, bh, acc[ts], 0, 0, 0);
      }
    }
    __syncthreads();
  }

#pragma unroll
  for (int ts = 0; ts < 8; ++ts) {
    const int t = t0 + wv*128 + ts*16 + n16;
#pragma unroll
    for (int r = 0; r < 4; ++r) {
      const int b = quad*4 + r;
      if (b < NBATCH)
        atomicAdd(wet + (size_t)b*TSAMP + t, acc[ts][r] * WET_DESCALE);
    }
  }
}

// K16: out = dry*(1-mix) + wet*mix
__global__ __launch_bounds__(256) void k_out(const float* __restrict__ dry,
                                             const float* __restrict__ wet,
                                             const float* __restrict__ mix,
                                             float* __restrict__ out) {
  const int b = blockIdx.y;
  const int t = blockIdx.x*1024 + threadIdx.x*4;
  const float m = mix[b];
  const float4 d = *(const float4*)(dry + t);
  const float4 w = *(const float4*)(wet + (size_t)b*TSAMP + t);
  float* o = out + (size_t)b*TSAMP + t;
  o[0] = d.x*(1.f-m) + w.x*m;
  o[1] = d.y*(1.f-m) + w.y*m;
  o[2] = d.z*(1.f-m) + w.z*m;
  o[3] = d.w*(1.f-m) + w.w*m;
}

// ------------------------------------------------------------------
extern "C" void kernel_launch(void* const* d_in, const int* in_sizes, int n_in,
                              void* d_out, int out_size, void* d_ws, size_t ws_size,
                              hipStream_t stream) {
  (void)in_sizes; (void)n_in; (void)out_size; (void)ws_size;
  const float* x      = (const float*)d_in[0];
  const float* bank   = (const float*)d_in[1];
  const float* w_net  = (const float*)d_in[2];
  const float* b_net  = (const float*)d_in[3];
  const float* attn_w = (const float*)d_in[4];
  const float* attn_b = (const float*)d_in[5];
  const float* a_hw = (const float*)d_in[6];
  const float* a_hb = (const float*)d_in[7];
  const float* a_ow = (const float*)d_in[8];
  const float* a_ob = (const float*)d_in[9];
  const float* t_hw = (const float*)d_in[10];
  const float* t_hb = (const float*)d_in[11];
  const float* t_ow = (const float*)d_in[12];
  const float* t_ob = (const float*)d_in[13];
  const float* m_hw = (const float*)d_in[14];
  const float* m_hb = (const float*)d_in[15];
  const float* m_ow = (const float*)d_in[16];
  const float* m_ob = (const float*)d_in[17];
  const float* atoms_dict    = (const float*)d_in[18];
  const float* transfer_dict = (const float*)d_in[19];
  const float* rooms  = (const float*)d_in[20];
  const float* room_w = (const float*)d_in[21];
  const float* room_b = (const float*)d_in[22];
  const float* mix_w  = (const float*)d_in[23];
  const float* mix_b  = (const float*)d_in[24];
  float* out = (float*)d_out;

  // ---- workspace (~204 MB): H | t1 | t2 | weights | stats (R11-proven)
  float* ws = (float*)d_ws;
  const size_t S = (size_t)CCH * TSAMP;
  float* H  = ws;                               // [B][T][C]
  float* t1 = ws + (size_t)33554432;
  float* t2 = ws + (size_t)41943040;
  _Float16* whi = (_Float16*)(ws + (size_t)50331648);
  _Float16* wlo = whi + 245760;
  _Float16* bhi = wlo + 245760;
  _Float16* blo = bhi + 65536;
  double* sums   = (double*)(ws + (size_t)50642944);   // 16 doubles
  float* attnraw = ws + (size_t)50642976;              // 8*32768
  float* pm      = attnraw + (size_t)NBATCH*TSAMP;     // 8*256*128

  size_t off = 33554432;                       // scratch base (aliases t1)
  float* scal  = ws + off; off += 8;
  float* vals  = ws + off; off += NROWS;
  int*   idxs  = (int*)(ws + off); off += NROWS;
  float* p_atoms = ws + off; off += (size_t)NROWS*NATOMS;
  float* p_trans = ws + off; off += (size_t)NROWS*NTRANS;
  float* amps  = ws + off; off += NROWS;
  float* av    = ws + off; off += (size_t)NROWS*ASIZE;
  float* trans = ws + off; off += (size_t)NROWS*TSIZE;
  float* ev    = ws + off; off += (size_t)NROWS*TSIZE;
  float* dry   = ws + off; off += TSAMP;
  float* roomp = ws + off; off += 64;
  float* mix   = ws + off; off += 8;
  float* wet   = ws + off; off += (size_t)NBATCH*TSAMP;
  float* cand_v = ws + off; off += 4096;
  int*   cand_i = (int*)(ws + off); off += 4096;
  _Float16* imphi = (_Float16*)(ws + off); off += (size_t)NBATCH*TSAMP/2;
  _Float16* drev  = (_Float16*)(ws + off); off += (TSAMP + 1088)/2 + 4;
  // scratch ends ~38.6M floats < t2 start — disjoint.

  k_prep<<<1216, 256, 0, stream>>>(w_net, bank, whi, wlo, bhi, blo, sums);
  k_front_mfma<<<dim3(256, 8), 256, 0, stream>>>(x, bhi, blo, H);

  const int dil[5] = {1, 3, 9, 27, 1};
  for (int p = 0; p < 4; ++p) {            // 2 batches per dispatch
    float* Hp = H + (size_t)(2*p) * S;
    float* io[6] = {Hp, t1, t2, t1, t2, Hp};
    for (int i = 0; i < 3; ++i) {          // d = 1, 3, 9: 128-t tiles
      const int d = dil[i];
      const size_t smem = (size_t)(128 + 2*d) * 544;
      k_dil128<<<dim3(256, 2), 256, smem, stream>>>(
          io[i], whi + (size_t)i*49152, wlo + (size_t)i*49152, b_net + i*CCH,
          io[i+1], d);
    }
    {                                      // d = 27: 80-t tiles
      const size_t smem = (size_t)134 * 544;
      k_dil80<<<dim3(410, 2), 256, smem, stream>>>(
          io[3], whi + (size_t)3*49152, wlo + (size_t)3*49152, b_net + 3*CCH,
          io[4]);
    }
    {                                      // last layer d=1: 128-t + stats
      const int d = dil[4];
      const size_t smem = (size_t)(128 + 2*d) * 544;
      k_dil_last<<<dim3(256, 2), 256, smem, stream>>>(
          io[4], whi + (size_t)4*49152, wlo + (size_t)4*49152, b_net + 4*CCH,
          io[5], d, attn_w, sums, attnraw, pm, 2*p);
    }
  }

  k_zero<<<1024, 256, 0, stream>>>(wet, drev);
  k_finish<<<8, 128, 0, stream>>>(sums, pm, room_w, room_b, mix_w, mix_b,
                                  scal, roomp, mix);
  k_topk1<<<dim3(16, 8), 256, 0, stream>>>(attnraw, scal, attn_b, cand_v, cand_i);
  k_topk2<<<8, 512, 0, stream>>>(cand_v, cand_i, vals, idxs);
  k_mlp<<<256, 128, 0, stream>>>(H, scal, vals, idxs,
                                 a_hw, a_hb, a_ow, a_ob,
                                 t_hw, t_hb, t_ow, t_ob,
                                 m_hw, m_hb, m_ow, m_ob,
                                 p_atoms, p_trans, amps);
  k_atoms_mm<<<256, 256, 0, stream>>>(p_atoms, atoms_dict, av);
  k_trans_mm<<<dim3(4, 256), 256, 0, stream>>>(p_trans, transfer_dict, trans);
  k_ev<<<dim3(8, 256), 256, 0, stream>>>(trans, av, amps, ev);
  k_dry<<<128, 256, 0, stream>>>(ev, idxs, dry, drev);
  k_impulse<<<dim3(32, 8), 256, 0, stream>>>(roomp, rooms, imphi);
  k_wet_mfma<<<dim3(64, 8), 256, 0, stream>>>(drev, imphi, wet);
  k_out<<<dim3(32, 8), 256, 0, stream>>>(dry, wet, mix, out);
}